// Round 12
// baseline (302.970 us; speedup 1.0000x reference)
//
#include <hip/hip_runtime.h>
#include <math.h>

#define B_ 32
#define F_ 128
#define H_ 256
#define N_ 2048
#define L_ 2
#define E_ 262144
#define NN_ 65536          // B_*N_
// DEG = E/(B*N) = 4

typedef __attribute__((ext_vector_type(8))) short short8;   // 8 bf16 = 4 VGPRs (MFMA A/B frag)
typedef __attribute__((ext_vector_type(4))) float f32x4;    // MFMA C/D frag
typedef __attribute__((ext_vector_type(2))) float f32x2;    // packed-FP32 pair (v_pk_*_f32)

static __device__ __forceinline__ unsigned short f2bf(float f) {
  unsigned int u = __float_as_uint(f);
  u += 0x7FFF + ((u >> 16) & 1);      // round-to-nearest-even
  return (unsigned short)(u >> 16);
}
static __device__ __forceinline__ float bf2f(unsigned short u) {
  return __uint_as_float(((unsigned int)u) << 16);
}
// 2×f32 -> packed 2×bf16 in one u32 (RNE), single instruction
static __device__ __forceinline__ unsigned int pk_bf16(float lo, float hi) {
  unsigned int r;
  asm("v_cvt_pk_bf16_f32 %0, %1, %2" : "=v"(r) : "v"(lo), "v"(hi));
  return r;
}

// async global->LDS, 16B per lane; LDS dest = wave-uniform base + lane*16
typedef const __attribute__((address_space(1))) unsigned int* as1p;
typedef __attribute__((address_space(3))) unsigned int* as3p;
static __device__ __forceinline__ void gload16(const void* g, void* l) {
  __builtin_amdgcn_global_load_lds((as1p)g, (as3p)l, 16, 0, 0);
}

// ---------------- mega1: deg | wconv | h0 | meand_g (all independent) ----------------
// blocks: [0,1024) deg ; [1024,1280) wconv ; [1280,1312) h0 ; [1312,3360) meand_g
__global__ void mega1_kernel(const int* __restrict__ ei, int* __restrict__ deg,
                             const float* __restrict__ Wm, const float* __restrict__ Wu,
                             unsigned short* __restrict__ Wt1, unsigned short* __restrict__ Wut,
                             const float* __restrict__ x, const float* __restrict__ W_in,
                             const float* __restrict__ b_in, float* __restrict__ h0,
                             const float* __restrict__ positions,
                             const float* __restrict__ Wg1, const float* __restrict__ bg1,
                             const float* __restrict__ Wg2, const float* __restrict__ bg2,
                             float* __restrict__ g) {
  __shared__ float red[256];
  __shared__ float hid[128];
  const int blk = blockIdx.x;
  const int t = threadIdx.x;
  if (blk < 1024) {
    // deg
    int e = blk * 256 + t;
    atomicAdd(&deg[ei[E_ + e]], 1);
  } else if (blk < 1280) {
    // wconv (frag-order weight conversion)
    int idx = (blk - 1024) * 256 + t;            // 0..65535
    int sel = idx >> 14;                          // 0,1: Wm l0,l1 ; 2,3: Wu l0,l1
    int rem = idx & 16383;
    if (sel < 2) {
      const float* W = Wm + (size_t)sel * 513 * H_;
      unsigned short* dst = Wt1 + (size_t)sel * 131072 + ((size_t)rem << 3);
      int gg = rem >> 13;
      int r2 = rem & 8191;
      int kc = r2 >> 11, w = (r2 >> 9) & 3, ks = (r2 >> 8) & 1, ni = (r2 >> 6) & 3, lane = r2 & 63;
      int r = lane & 15, q = lane >> 4;
      int n  = (w << 6) + (ni << 4) + r;
      int kb = (gg << 8) + (kc << 6) + (ks << 5) + (q << 3);
#pragma unroll
      for (int j = 0; j < 8; ++j)
        dst[j] = f2bf(W[(size_t)(kb + j) * H_ + n]);
    } else {
      const float* W = Wu + (size_t)(sel - 2) * 512 * H_;
      unsigned short* dst = Wut + (size_t)(sel - 2) * 131072 + ((size_t)rem << 3);
      int kc = rem >> 11, w = (rem >> 9) & 3, ks = (rem >> 8) & 1, ni = (rem >> 6) & 3, lane = rem & 63;
      int r = lane & 15, q = lane >> 4;
      int n  = (w << 6) + (ni << 4) + r;
      int kb = (kc << 6) + (ks << 5) + (q << 3);
#pragma unroll
      for (int j = 0; j < 8; ++j)
        dst[j] = f2bf(W[(size_t)(kb + j) * H_ + n]);
    }
  } else if (blk < 1312) {
    // h0
    int b = blk - 1280;
    float acc = b_in[t];
#pragma unroll 8
    for (int k = 0; k < F_; ++k)
      acc += x[b * F_ + k] * W_in[k * H_ + t];
    h0[b * H_ + t] = acc;
  } else {
    // meand_g: one block per node n
    int n = blk - 1312;
    float px = positions[n * 3 + 0], py = positions[n * 3 + 1], pz = positions[n * 3 + 2];
    float s = 0.f;
    for (int j = t; j < N_; j += 256) {
      float dx = px - positions[j * 3 + 0];
      float dy = py - positions[j * 3 + 1];
      float dz = pz - positions[j * 3 + 2];
      s += sqrtf(dx * dx + dy * dy + dz * dz);
    }
    red[t] = s;
    __syncthreads();
    for (int off = 128; off > 0; off >>= 1) {
      if (t < off) red[t] += red[t + off];
      __syncthreads();
    }
    float md = red[0] / (float)(N_ - 1);
    if (t < 128) {
      float w = Wg1[t] + Wg1[128 + t] + Wg1[256 + t];
      hid[t] = fmaxf(md * w + bg1[t], 0.f);
    }
    __syncthreads();
    float acc = bg2[t];
#pragma unroll 8
    for (int k = 0; k < 128; ++k)
      acc += hid[k] * Wg2[k * H_ + t];
    g[n * H_ + t] = acc;
  }
}

// ---------------- CSR scans (unchanged, small) ----------------

__global__ void scan1_kernel(const int* __restrict__ deg, int* __restrict__ bsum) {
  __shared__ int red[256];
  int t = threadIdx.x;
  red[t] = deg[blockIdx.x * 256 + t];
  __syncthreads();
  for (int off = 128; off > 0; off >>= 1) {
    if (t < off) red[t] += red[t + off];
    __syncthreads();
  }
  if (t == 0) bsum[blockIdx.x] = red[0];
}

__global__ void scan2_kernel(int* __restrict__ bsum) {
  __shared__ int s[256];
  int t = threadIdx.x;
  s[t] = bsum[t];
  __syncthreads();
  for (int off = 1; off < 256; off <<= 1) {
    int v = (t >= off) ? s[t - off] : 0;
    __syncthreads();
    s[t] += v;
    __syncthreads();
  }
  bsum[t] = (t == 0) ? 0 : s[t - 1];
}

// ---------------- mega2: scan3 | initpack ----------------
// blocks [0,256): scan3 ; [256, 8964): initpack
__global__ void mega2_kernel(const int* __restrict__ deg, const int* __restrict__ bsum,
                             int* __restrict__ cur, int* __restrict__ rowptr,
                             const float* __restrict__ h0, const float* __restrict__ g,
                             const float* __restrict__ positions,
                             unsigned short* __restrict__ hbf,
                             unsigned short* __restrict__ hg,
                             float* __restrict__ pos4) {
  __shared__ int s[256];
  const int blk0 = blockIdx.x;
  const int t = threadIdx.x;
  if (blk0 < 256) {
    // scan3: writes BOTH cur and rowptr
    int i = blk0 * 256 + t;
    s[t] = deg[i];
    __syncthreads();
    for (int off = 1; off < 256; off <<= 1) {
      int v = (t >= off) ? s[t - off] : 0;
      __syncthreads();
      s[t] += v;
      __syncthreads();
    }
    int excl = (t == 0) ? 0 : s[t - 1];
    int v = bsum[blk0] + excl;
    cur[i] = v;
    rowptr[i] = v;
    return;
  }
  const int blk = blk0 - 256;
  if (blk < 8192) {
    int idx = blk * 256 + t;  // NN*32, 8 ch each
    int row = idx >> 5;
    int c8 = (idx & 31) << 3;
    const float* hp = h0 + (row >> 11) * H_ + c8;
    const float* gp = g + (row & (N_ - 1)) * H_ + c8;
    const float4 a = *(const float4*)hp;
    const float4 a2 = *(const float4*)(hp + 4);
    const float4 b = *(const float4*)gp;
    const float4 b2 = *(const float4*)(gp + 4);
    short8 v;
    v[0] = (short)f2bf(a.x + b.x);  v[1] = (short)f2bf(a.y + b.y);
    v[2] = (short)f2bf(a.z + b.z);  v[3] = (short)f2bf(a.w + b.w);
    v[4] = (short)f2bf(a2.x + b2.x); v[5] = (short)f2bf(a2.y + b2.y);
    v[6] = (short)f2bf(a2.z + b2.z); v[7] = (short)f2bf(a2.w + b2.w);
    *(short8*)(hbf + (((size_t)row) << 8) + c8) = v;
  } else if (blk < 8452) {
    int idx = (blk - 8192) * 256 + t;  // 2080*32, 8 ch each
    int row = idx >> 5;
    int c8 = (idx & 31) << 3;
    const float* src = (row < 2048) ? (g + (size_t)row * H_ + c8)
                                    : (h0 + (size_t)(row - 2048) * H_ + c8);
    const float4 a = *(const float4*)src;
    const float4 a2 = *(const float4*)(src + 4);
    short8 v;
    v[0] = (short)f2bf(a.x);  v[1] = (short)f2bf(a.y);
    v[2] = (short)f2bf(a.z);  v[3] = (short)f2bf(a.w);
    v[4] = (short)f2bf(a2.x); v[5] = (short)f2bf(a2.y);
    v[6] = (short)f2bf(a2.z); v[7] = (short)f2bf(a2.w);
    *(short8*)(hg + (((size_t)row) << 8) + c8) = v;
  } else {
    int n = (blk - 8452) * 256 + t;   // 0..NN-1
    int src = (n & (N_ - 1)) * 3;
    float4 v;
    v.x = positions[src + 0];
    v.y = positions[src + 1];
    v.z = positions[src + 2];
    v.w = 0.f;
    *(float4*)(pos4 + ((size_t)n << 2)) = v;
  }
}

// ============ counted-vmcnt pipelined GEMM (K=32 phases, 4 buffers, depth-3) ============
// (round-5 proven structure)

#define GEMM_IDS(BID)                                                \
  const int t = threadIdx.x;                                         \
  const int m0 = (BID) << 6;                                         \
  const int wu = __builtin_amdgcn_readfirstlane(t >> 6);             \
  const int lane = t & 63;                                           \
  const int q = lane >> 4;                                           \
  const int r = lane & 15;                                           \
  const int arow = lane >> 2;                                        \
  const int aq = (lane & 3) ^ ((lane >> 2) & 3);   /* pre-swizzled src quad */

#define STAGE_P(P, abase)                                                                \
  do {                                                                                   \
    gload16((abase) + (((size_t)(m0 + (wu << 4) + arow)) << 8) + (((P) & 7) << 5) +      \
                (aq << 3),                                                               \
            &sA[(P) & 3][wu << 9]);                                                      \
    _Pragma("unroll")                                                                    \
    for (int j_ = 0; j_ < 4; ++j_)                                                       \
      gload16(Wt + (((size_t)((P) >> 1)) << 14) + (wu << 12) + (((P) & 1) << 11) +       \
                  (j_ << 9) + (lane << 3),                                               \
              &sB[(P) & 3][(wu << 11) + (j_ << 9)]);                                     \
  } while (0)

#define COMPUTE_P(P)                                                                     \
  do {                                                                                   \
    short8 af[4], bfr[4];                                                                \
    _Pragma("unroll")                                                                    \
    for (int mi = 0; mi < 4; ++mi)                                                       \
      af[mi] = *(const short8*)(&sA[(P) & 3][((mi * 16 + r) << 5) +                      \
                                             ((q ^ (r & 3)) << 3)]);                     \
    _Pragma("unroll")                                                                    \
    for (int ni = 0; ni < 4; ++ni)                                                       \
      bfr[ni] = *(const short8*)(&sB[(P) & 3][(wu << 11) + (ni << 9) + (lane << 3)]);    \
    _Pragma("unroll")                                                                    \
    for (int mi = 0; mi < 4; ++mi)                                                       \
      _Pragma("unroll")                                                                  \
      for (int ni = 0; ni < 4; ++ni)                                                     \
        acc[mi][ni] = __builtin_amdgcn_mfma_f32_16x16x32_bf16(af[mi], bfr[ni],           \
                                                              acc[mi][ni], 0, 0, 0);     \
  } while (0)

// 16-phase wait schedule
#define WAIT_BAR(P)                                                       \
  do {                                                                    \
    if ((P) <= 13)      asm volatile("s_waitcnt vmcnt(10)" ::: "memory"); \
    else if ((P) == 14) asm volatile("s_waitcnt vmcnt(5)" ::: "memory");  \
    else                asm volatile("s_waitcnt vmcnt(0)" ::: "memory");  \
    __builtin_amdgcn_s_barrier();                                         \
    asm volatile("" ::: "memory");                                        \
  } while (0)

// 8-phase wait schedule
#define WAIT_BAR8(P)                                                      \
  do {                                                                    \
    if ((P) <= 5)       asm volatile("s_waitcnt vmcnt(10)" ::: "memory"); \
    else if ((P) == 6)  asm volatile("s_waitcnt vmcnt(5)" ::: "memory");  \
    else                asm volatile("s_waitcnt vmcnt(0)" ::: "memory");  \
    __builtin_amdgcn_s_barrier();                                         \
    asm volatile("" ::: "memory");                                        \
  } while (0)

#define ACC_ZERO()                                   \
  _Pragma("unroll")                                  \
  for (int mi = 0; mi < 4; ++mi)                     \
    _Pragma("unroll")                                \
    for (int ni = 0; ni < 4; ++ni)                   \
      acc[mi][ni] = (f32x4){0.f, 0.f, 0.f, 0.f};

// ---------------- mega3: scatter | gemm1_small | Uc-small-GEMM ----------------
// blocks [0,1024): scatter ; [1024,1057): gemm1_small (Wm l0, 16 phases)
// [1057,1090): Uc GEMM  (hg @ Wu_l0[0:256,:] -> Uc, 8 phases)
__launch_bounds__(256)
__global__ void mega3_kernel(const int* __restrict__ ei, int* __restrict__ cur,
                             int* __restrict__ src_s,
                             const unsigned short* __restrict__ hg,
                             const unsigned short* __restrict__ Wtm,   // Wm layer0 frag
                             const unsigned short* __restrict__ Wtu,   // Wu layer0 frag
                             const float* __restrict__ bm,
                             float* __restrict__ Xc, float* __restrict__ Zc,
                             float* __restrict__ Uc) {
  __shared__ __align__(16) unsigned short sA[4][2048];
  __shared__ __align__(16) unsigned short sB[4][8192];
  const int blk = blockIdx.x;
  if (blk < 1024) {
    // scatter
    int e = blk * 256 + threadIdx.x;
    int s = ei[e], d = ei[E_ + e];
    int p = atomicAdd(&cur[d], 1);
    src_s[p] = s;
    return;
  }
  if (blk < 1057) {
    // gemm1_small: layer-0 rank decomposition (2112 rows, f32 out), K=512 of Wm
    const int bid = blk - 1024;
    const unsigned short* Wt = Wtm;
    GEMM_IDS(bid)

    f32x4 acc[4][4];
    ACC_ZERO();

    STAGE_P(0, hg); STAGE_P(1, hg); STAGE_P(2, hg);
#pragma unroll
    for (int p = 0; p < 16; ++p) {
      WAIT_BAR(p);
      if (p + 3 < 16) STAGE_P(p + 3, hg);
      COMPUTE_P(p);
      if (p == 7) {
#pragma unroll
        for (int ni = 0; ni < 4; ++ni) {
          int n = (wu << 6) + ni * 16 + r;
#pragma unroll
          for (int mi = 0; mi < 4; ++mi)
#pragma unroll
            for (int reg = 0; reg < 4; ++reg) {
              size_t idx = (((size_t)(m0 + mi * 16 + q * 4 + reg)) << 8) + n;
              Xc[idx] = acc[mi][ni][reg];
              acc[mi][ni][reg] = 0.f;
            }
        }
      }
    }

    const int isH0 = (bid == 32);   // rows 2048.. carry h0 -> bias lives here
#pragma unroll
    for (int ni = 0; ni < 4; ++ni) {
      int n = (wu << 6) + ni * 16 + r;
      float bmn = isH0 ? bm[n] : 0.f;
#pragma unroll
      for (int mi = 0; mi < 4; ++mi)
#pragma unroll
        for (int reg = 0; reg < 4; ++reg) {
          size_t idx = (((size_t)(m0 + mi * 16 + q * 4 + reg)) << 8) + n;
          Zc[idx] = acc[mi][ni][reg] + bmn;
        }
    }
    return;
  }
  // Uc GEMM: hg @ Wu_l0 rows 0..255 (pieces 0..3), 8 phases, f32 out (no bias)
  {
    const int bid = blk - 1057;
    const unsigned short* Wt = Wtu;
    GEMM_IDS(bid)

    f32x4 acc[4][4];
    ACC_ZERO();

    STAGE_P(0, hg); STAGE_P(1, hg); STAGE_P(2, hg);
#pragma unroll
    for (int p = 0; p < 8; ++p) {
      WAIT_BAR8(p);
      if (p + 3 < 8) STAGE_P(p + 3, hg);
      COMPUTE_P(p);
    }
#pragma unroll
    for (int ni = 0; ni < 4; ++ni) {
      int n = (wu << 6) + ni * 16 + r;
#pragma unroll
      for (int mi = 0; mi < 4; ++mi)
#pragma unroll
        for (int reg = 0; reg < 4; ++reg) {
          size_t idx = (((size_t)(m0 + mi * 16 + q * 4 + reg)) << 8) + n;
          Uc[idx] = acc[mi][ni][reg];
        }
    }
  }
}

// ---------------- GEMM1: 16 phases (p0-7: g=0 -> X bf16, p8-15: g=1 -> Zb bf16) ----------------
__launch_bounds__(256)
__global__ void gemm1_mfma(const unsigned short* __restrict__ hbf,
                           const unsigned short* __restrict__ Wt,
                           const float* __restrict__ bm,
                           unsigned short* __restrict__ X, unsigned short* __restrict__ Zb) {
  __shared__ __align__(16) unsigned short sA[4][2048];
  __shared__ __align__(16) unsigned short sB[4][8192];
  GEMM_IDS(blockIdx.x)

  f32x4 acc[4][4];
  ACC_ZERO();

  STAGE_P(0, hbf); STAGE_P(1, hbf); STAGE_P(2, hbf);
#pragma unroll
  for (int p = 0; p < 16; ++p) {
    WAIT_BAR(p);
    if (p + 3 < 16) STAGE_P(p + 3, hbf);
    COMPUTE_P(p);
    if (p == 7) {
      // g=0 half done: store X, reset acc
#pragma unroll
      for (int ni = 0; ni < 4; ++ni) {
        int n = (wu << 6) + ni * 16 + r;
#pragma unroll
        for (int mi = 0; mi < 4; ++mi)
#pragma unroll
          for (int reg = 0; reg < 4; ++reg) {
            size_t idx = (((size_t)(m0 + mi * 16 + q * 4 + reg)) << 8) + n;
            X[idx] = f2bf(acc[mi][ni][reg]);
            acc[mi][ni][reg] = 0.f;
          }
      }
    }
  }

  // g=1 half: store Zb (+bm)
#pragma unroll
  for (int ni = 0; ni < 4; ++ni) {
    int n = (wu << 6) + ni * 16 + r;
    float bmn = bm[n];
#pragma unroll
    for (int mi = 0; mi < 4; ++mi)
#pragma unroll
      for (int reg = 0; reg < 4; ++reg) {
        size_t idx = (((size_t)(m0 + mi * 16 + q * 4 + reg)) << 8) + n;
        Zb[idx] = f2bf(acc[mi][ni][reg] + bmn);
      }
  }
}

// ---------------- edge kernels: 4 nodes/wave sequential, scalar CSR, 4-wide groups ----------------
static __device__ __forceinline__ void edge_core(
    const float4 pn, const float4 q,
    f32x2 x01, f32x2 x23,
    const f32x2 z01, const f32x2 z23,
    const f32x2 wl01, const f32x2 wl23,
    const f32x2 wp01, const f32x2 wp23,
    f32x2& a01, f32x2& a23,
    float& pdx, float& pdy, float& pdz) {
  const float dx = pn.x - q.x, dy = pn.y - q.y, dz = pn.z - q.z;
  const float d = sqrtf(dx * dx + dy * dy + dz * dz + 1e-12f);
  f32x2 dd; dd[0] = d; dd[1] = d;
  f32x2 v01 = x01 + z01 + dd * wl01;          // v_pk_add + v_pk_fma
  f32x2 v23 = x23 + z23 + dd * wl23;
  v01[0] = fmaxf(v01[0], 0.f); v01[1] = fmaxf(v01[1], 0.f);
  v23[0] = fmaxf(v23[0], 0.f); v23[1] = fmaxf(v23[1], 0.f);
  a01 += v01; a23 += v23;
  const f32x2 cpv = v01 * wp01 + v23 * wp23;  // v_pk_mul + v_pk_fma
  const float cp = cpv[0] + cpv[1];
  pdx += dx * cp; pdy += dy * cp; pdz += dz * cp;
}

// no-pos variant: final-layer position update is dead code in the reference
static __device__ __forceinline__ void edge_core_np(
    const float4 pn, const float4 q,
    f32x2 x01, f32x2 x23,
    const f32x2 z01, const f32x2 z23,
    const f32x2 wl01, const f32x2 wl23,
    f32x2& a01, f32x2& a23) {
  const float dx = pn.x - q.x, dy = pn.y - q.y, dz = pn.z - q.z;
  const float d = sqrtf(dx * dx + dy * dy + dz * dz + 1e-12f);
  f32x2 dd; dd[0] = d; dd[1] = d;
  f32x2 v01 = x01 + z01 + dd * wl01;
  f32x2 v23 = x23 + z23 + dd * wl23;
  v01[0] = fmaxf(v01[0], 0.f); v01[1] = fmaxf(v01[1], 0.f);
  v23[0] = fmaxf(v23[0], 0.f); v23[1] = fmaxf(v23[1], 0.f);
  a01 += v01; a23 += v23;
}

static __device__ __forceinline__ void edge_do_np(
    const float4 pn, const float4 q, const uint2 xv,
    const f32x2 z01, const f32x2 z23,
    const f32x2 wl01, const f32x2 wl23,
    f32x2& a01, f32x2& a23) {
  f32x2 x01, x23;
  x01[0] = __uint_as_float(xv.x << 16);
  x01[1] = __uint_as_float(xv.x & 0xffff0000u);
  x23[0] = __uint_as_float(xv.y << 16);
  x23[1] = __uint_as_float(xv.y & 0xffff0000u);
  edge_core_np(pn, q, x01, x23, z01, z23, wl01, wl23, a01, a23);
}

static __device__ __forceinline__ void edge_do0(
    const float4 pn, const float4 q, const float4 xg, const float4 xh,
    const f32x2 z01, const f32x2 z23,
    const f32x2 wl01, const f32x2 wl23,
    const f32x2 wp01, const f32x2 wp23,
    f32x2& a01, f32x2& a23,
    float& pdx, float& pdy, float& pdz) {
  f32x2 x01, x23;
  x01[0] = xg.x + xh.x; x01[1] = xg.y + xh.y;
  x23[0] = xg.z + xh.z; x23[1] = xg.w + xh.w;
  edge_core(pn, q, x01, x23, z01, z23, wl01, wl23, wp01, wp23, a01, a23, pdx, pdy, pdz);
}

// layer-1 edge (FINAL layer): pos/coef path removed; 4 nodes per wave sequential
__launch_bounds__(256)
__global__ void edge_kernel(const unsigned short* __restrict__ X,
                            const unsigned short* __restrict__ Zb,
                            const float* __restrict__ pos_c,   // stride-4
                            const int* __restrict__ rowptr, const int* __restrict__ src_s,
                            const float* __restrict__ wl,
                            unsigned short* __restrict__ aggb) {
  const int wid = (blockIdx.x * 256 + threadIdx.x) >> 6;   // wave id
  const int lane = threadIdx.x & 63;

  // hoisted per-lane weights (node-independent)
  const float4 wlv = *(const float4*)(wl + (lane << 2));
  const f32x2 wl01 = {wlv.x, wlv.y}, wl23 = {wlv.z, wlv.w};

  const unsigned short* Xl = X + (lane << 2);

  for (int sub = 0; sub < 4; ++sub) {
    const int n = __builtin_amdgcn_readfirstlane((wid << 2) + sub);

    const int e0 = rowptr[n];
    const int e1 = (n == NN_ - 1) ? E_ : rowptr[n + 1];

    const uint2 zv = *(const uint2*)(Zb + (((size_t)n) << 8) + (lane << 2));
    f32x2 z01, z23;
    z01[0] = __uint_as_float(zv.x << 16);
    z01[1] = __uint_as_float(zv.x & 0xffff0000u);
    z23[0] = __uint_as_float(zv.y << 16);
    z23[1] = __uint_as_float(zv.y & 0xffff0000u);

    const float4 pn = *(const float4*)(pos_c + ((size_t)n << 2));
    f32x2 a01 = {0.f, 0.f}, a23 = {0.f, 0.f};

    int e = e0;
    for (; e + 4 <= e1; e += 4) {
      const int s0 = src_s[e], s1 = src_s[e + 1], s2 = src_s[e + 2], s3 = src_s[e + 3];
      const float4 q0 = *(const float4*)(pos_c + ((size_t)s0 << 2));
      const float4 q1 = *(const float4*)(pos_c + ((size_t)s1 << 2));
      const float4 q2 = *(const float4*)(pos_c + ((size_t)s2 << 2));
      const float4 q3 = *(const float4*)(pos_c + ((size_t)s3 << 2));
      const uint2 x0 = *(const uint2*)(Xl + (((size_t)s0) << 8));
      const uint2 x1 = *(const uint2*)(Xl + (((size_t)s1) << 8));
      const uint2 x2 = *(const uint2*)(Xl + (((size_t)s2) << 8));
      const uint2 x3 = *(const uint2*)(Xl + (((size_t)s3) << 8));
      edge_do_np(pn, q0, x0, z01, z23, wl01, wl23, a01, a23);
      edge_do_np(pn, q1, x1, z01, z23, wl01, wl23, a01, a23);
      edge_do_np(pn, q2, x2, z01, z23, wl01, wl23, a01, a23);
      edge_do_np(pn, q3, x3, z01, z23, wl01, wl23, a01, a23);
    }
    if (e + 2 <= e1) {
      const int s0 = src_s[e], s1 = src_s[e + 1];
      const float4 q0 = *(const float4*)(pos_c + ((size_t)s0 << 2));
      const float4 q1 = *(const float4*)(pos_c + ((size_t)s1 << 2));
      const uint2 x0 = *(const uint2*)(Xl + (((size_t)s0) << 8));
      const uint2 x1 = *(const uint2*)(Xl + (((size_t)s1) << 8));
      edge_do_np(pn, q0, x0, z01, z23, wl01, wl23, a01, a23);
      edge_do_np(pn, q1, x1, z01, z23, wl01, wl23, a01, a23);
      e += 2;
    }
    if (e < e1) {
      const int s0 = src_s[e];
      const float4 q0 = *(const float4*)(pos_c + ((size_t)s0 << 2));
      const uint2 x0 = *(const uint2*)(Xl + (((size_t)s0) << 8));
      edge_do_np(pn, q0, x0, z01, z23, wl01, wl23, a01, a23);
    }

    uint2 av;
    av.x = pk_bf16(a01[0], a01[1]);
    av.y = pk_bf16(a23[0], a23[1]);
    *(uint2*)(aggb + (((size_t)n) << 8) + (lane << 2)) = av;
  }
}

// layer-0 edge: X/Z from rank-decomposed f32 tables; 4 nodes per wave sequential
__launch_bounds__(256)
__global__ void edge0_kernel(const float* __restrict__ Xc,
                             const float* __restrict__ Zc,
                             const float* __restrict__ pos_c,   // stride-4
                             const int* __restrict__ rowptr, const int* __restrict__ src_s,
                             const float* __restrict__ wl, const float* __restrict__ wp,
                             unsigned short* __restrict__ aggb, float* __restrict__ pos_o) {
  const int wid = (blockIdx.x * 256 + threadIdx.x) >> 6;   // wave id
  const int lane = threadIdx.x & 63;

  // hoisted per-lane weights (node-independent)
  const float4 wlv = *(const float4*)(wl + (lane << 2));
  const float4 wpv = *(const float4*)(wp + (lane << 2));
  const f32x2 wl01 = {wlv.x, wlv.y}, wl23 = {wlv.z, wlv.w};
  const f32x2 wp01 = {wpv.x, wpv.y}, wp23 = {wpv.z, wpv.w};

  const float* Xl = Xc + (lane << 2);
  const float* Zl = Zc + (lane << 2);

  for (int sub = 0; sub < 4; ++sub) {
    const int n = __builtin_amdgcn_readfirstlane((wid << 2) + sub);

    const int e0 = rowptr[n];
    const int e1 = (n == NN_ - 1) ? E_ : rowptr[n + 1];

    // z = Zg[node] + Zh0[batch] (Zh0 carries bm)
    const float4 zg = *(const float4*)(Zl + (((size_t)(n & (N_ - 1))) << 8));
    const float4 zh = *(const float4*)(Zl + (((size_t)(2048 + (n >> 11))) << 8));
    f32x2 z01, z23;
    z01[0] = zg.x + zh.x; z01[1] = zg.y + zh.y;
    z23[0] = zg.z + zh.z; z23[1] = zg.w + zh.w;

    const float4 pn = *(const float4*)(pos_c + ((size_t)n << 2));
    f32x2 a01 = {0.f, 0.f}, a23 = {0.f, 0.f};
    float pdx = 0.f, pdy = 0.f, pdz = 0.f;

    int e = e0;
    for (; e + 4 <= e1; e += 4) {
      const int s0 = src_s[e], s1 = src_s[e + 1], s2 = src_s[e + 2], s3 = src_s[e + 3];
      const float4 q0 = *(const float4*)(pos_c + ((size_t)s0 << 2));
      const float4 q1 = *(const float4*)(pos_c + ((size_t)s1 << 2));
      const float4 q2 = *(const float4*)(pos_c + ((size_t)s2 << 2));
      const float4 q3 = *(const float4*)(pos_c + ((size_t)s3 << 2));
      const float4 xg0 = *(const float4*)(Xl + (((size_t)(s0 & (N_ - 1))) << 8));
      const float4 xh0 = *(const float4*)(Xl + (((size_t)(2048 + (s0 >> 11))) << 8));
      const float4 xg1 = *(const float4*)(Xl + (((size_t)(s1 & (N_ - 1))) << 8));
      const float4 xh1 = *(const float4*)(Xl + (((size_t)(2048 + (s1 >> 11))) << 8));
      const float4 xg2 = *(const float4*)(Xl + (((size_t)(s2 & (N_ - 1))) << 8));
      const float4 xh2 = *(const float4*)(Xl + (((size_t)(2048 + (s2 >> 11))) << 8));
      const float4 xg3 = *(const float4*)(Xl + (((size_t)(s3 & (N_ - 1))) << 8));
      const float4 xh3 = *(const float4*)(Xl + (((size_t)(2048 + (s3 >> 11))) << 8));
      edge_do0(pn, q0, xg0, xh0, z01, z23, wl01, wl23, wp01, wp23, a01, a23, pdx, pdy, pdz);
      edge_do0(pn, q1, xg1, xh1, z01, z23, wl01, wl23, wp01, wp23, a01, a23, pdx, pdy, pdz);
      edge_do0(pn, q2, xg2, xh2, z01, z23, wl01, wl23, wp01, wp23, a01, a23, pdx, pdy, pdz);
      edge_do0(pn, q3, xg3, xh3, z01, z23, wl01, wl23, wp01, wp23, a01, a23, pdx, pdy, pdz);
    }
    for (; e < e1; ++e) {
      const int s0 = src_s[e];
      const float4 q0 = *(const float4*)(pos_c + ((size_t)s0 << 2));
      const float4 xg0 = *(const float4*)(Xl + (((size_t)(s0 & (N_ - 1))) << 8));
      const float4 xh0 = *(const float4*)(Xl + (((size_t)(2048 + (s0 >> 11))) << 8));
      edge_do0(pn, q0, xg0, xh0, z01, z23, wl01, wl23, wp01, wp23, a01, a23, pdx, pdy, pdz);
    }

    uint2 av;
    av.x = pk_bf16(a01[0], a01[1]);
    av.y = pk_bf16(a23[0], a23[1]);
    *(uint2*)(aggb + (((size_t)n) << 8) + (lane << 2)) = av;

#pragma unroll
    for (int m = 1; m < 64; m <<= 1) {
      pdx += __shfl_xor(pdx, m, 64);
      pdy += __shfl_xor(pdy, m, 64);
      pdz += __shfl_xor(pdz, m, 64);
    }
    if (lane == 0) {
      float4 po;
      po.x = pn.x + pdx * 0.25f;
      po.y = pn.y + pdy * 0.25f;
      po.z = pn.z + pdz * 0.25f;
      po.w = 0.f;
      *(float4*)(pos_o + ((size_t)n << 2)) = po;
    }
  }
}

// ---------------- GEMM2 layer-0: rank-decomposed hbf half (acc init from Uc) ----------------
// acc = Uc[g-part] + Uc[h0-part]  (K=0..255 contribution), then 8 phases over aggb (K=256..511).
// Wt must point at Wu-layer0 frag pieces 4..7 (i.e. Wut + 65536).
__launch_bounds__(256)
__global__ void upd2_dec(unsigned short* __restrict__ hbf,
                         const unsigned short* __restrict__ aggb,
                         const unsigned short* __restrict__ Wt,
                         const float* __restrict__ Uc,
                         const float* __restrict__ bu) {
  __shared__ __align__(16) unsigned short sA[4][2048];
  __shared__ __align__(16) unsigned short sB[4][8192];
  GEMM_IDS(blockIdx.x)

  const int nn0 = m0 & (N_ - 1);   // block's 64 rows share one batch (64 | 2048)
  const int bb  = m0 >> 11;

  f32x4 acc[4][4];
  // acc init from Uc: 64 consecutive g-rows + one block-uniform h0 row.
#pragma unroll
  for (int ni = 0; ni < 4; ++ni) {
    int n = (wu << 6) + ni * 16 + r;
    float uh = Uc[(((size_t)(2048 + bb)) << 8) + n];
#pragma unroll
    for (int mi = 0; mi < 4; ++mi)
#pragma unroll
      for (int reg = 0; reg < 4; ++reg) {
        int rl = mi * 16 + q * 4 + reg;
        acc[mi][ni][reg] = Uc[(((size_t)(nn0 + rl)) << 8) + n] + uh;
      }
  }

  STAGE_P(0, aggb); STAGE_P(1, aggb); STAGE_P(2, aggb);
#pragma unroll
  for (int p = 0; p < 8; ++p) {
    WAIT_BAR8(p);
    if (p + 3 < 8) STAGE_P(p + 3, aggb);
    COMPUTE_P(p);
  }

  // epilogue: residual add; hbf rows are L2-hot
#pragma unroll
  for (int ni = 0; ni < 4; ++ni) {
    int n = (wu << 6) + ni * 16 + r;
    float buv = bu[n];
#pragma unroll
    for (int mi = 0; mi < 4; ++mi)
#pragma unroll
      for (int reg = 0; reg < 4; ++reg) {
        size_t idx = (((size_t)(m0 + mi * 16 + q * 4 + reg)) << 8) + n;
        float v = bf2f(hbf[idx]) + fmaxf(acc[mi][ni][reg] + buv, 0.f);
        hbf[idx] = f2bf(v);
      }
  }
}

// ---------------- GEMM2 final layer with fused W_out projection ----------------
__launch_bounds__(256)
__global__ void upd2_out(const unsigned short* __restrict__ hbf,
                         const unsigned short* __restrict__ aggb,
                         const unsigned short* __restrict__ Wt,
                         const float* __restrict__ bu,
                         const float* __restrict__ Wout, const float* __restrict__ bout,
                         float* __restrict__ out) {
  __shared__ __align__(16) unsigned short sA[4][2048];
  __shared__ __align__(16) unsigned short sB[4][8192];
  GEMM_IDS(blockIdx.x)

  f32x4 acc[4][4];
  ACC_ZERO();

  STAGE_P(0, hbf); STAGE_P(1, hbf); STAGE_P(2, hbf);
#pragma unroll
  for (int p = 0; p < 16; ++p) {
    WAIT_BAR(p);
    if (p + 3 < 16) {
      const unsigned short* ab = (p + 3 < 8) ? hbf : aggb;
      STAGE_P(p + 3, ab);
    }
    COMPUTE_P(p);
  }
  __syncthreads();                      // LDS reads done; safe to reuse sA for sRed
  float (*sRed)[64] = (float(*)[64])(&sA[0][0]);

  float dotp[4][4];
#pragma unroll
  for (int mi = 0; mi < 4; ++mi)
#pragma unroll
    for (int reg = 0; reg < 4; ++reg)
      dotp[mi][reg] = 0.f;

#pragma unroll
  for (int ni = 0; ni < 4; ++ni) {
    int n = (wu << 6) + ni * 16 + r;
    float buv = bu[n];
    float won = Wout[n];
#pragma unroll
    for (int mi = 0; mi < 4; ++mi)
#pragma unroll
      for (int reg = 0; reg < 4; ++reg) {
        size_t idx = (((size_t)(m0 + mi * 16 + q * 4 + reg)) << 8) + n;
        float v = bf2f(hbf[idx]) + fmaxf(acc[mi][ni][reg] + buv, 0.f);
        dotp[mi][reg] += v * won;
      }
  }
#pragma unroll
  for (int mask = 1; mask < 16; mask <<= 1)
#pragma unroll
    for (int mi = 0; mi < 4; ++mi)
#pragma unroll
      for (int reg = 0; reg < 4; ++reg)
        dotp[mi][reg] += __shfl_xor(dotp[mi][reg], mask, 64);
  if (r == 0) {
#pragma unroll
    for (int mi = 0; mi < 4; ++mi)
#pragma unroll
      for (int reg = 0; reg < 4; ++reg)
        sRed[wu][mi * 16 + q * 4 + reg] = dotp[mi][reg];
  }
  __syncthreads();
  if (t < 64)
    out[m0 + t] = sRed[0][t] + sRed[1][t] + sRed[2][t] + sRed[3][t] + bout[0];
}

// ---------------- launcher ----------------

extern "C" void kernel_launch(void* const* d_in, const int* in_sizes, int n_in,
                              void* d_out, int out_size, void* d_ws, size_t ws_size,
                              hipStream_t stream) {
  const float* x         = (const float*)d_in[0];
  const float* positions = (const float*)d_in[1];
  const float* W_in      = (const float*)d_in[2];
  const float* b_in      = (const float*)d_in[3];
  const float* Wg1       = (const float*)d_in[4];
  const float* bg1       = (const float*)d_in[5];
  const float* Wg2       = (const float*)d_in[6];
  const float* bg2       = (const float*)d_in[7];
  const float* Wm        = (const float*)d_in[8];
  const float* bm        = (const float*)d_in[9];
  const float* Wu        = (const float*)d_in[10];
  const float* bu        = (const float*)d_in[11];
  const float* Wp        = (const float*)d_in[12];
  const float* W_out     = (const float*)d_in[13];
  const float* b_out     = (const float*)d_in[14];
  const int*   ei        = (const int*)d_in[15];
  float* out = (float*)d_out;

  // workspace layout — sequential, non-overlapping (pos stride-4: 1 MB each)
  char* ws = (char*)d_ws;
  unsigned short* hbf   = (unsigned short*)(ws);                 //   0       +32 MB
  unsigned short* X     = (unsigned short*)(ws +  33554432UL);   //  32 MB    +32 MB
  unsigned short* Zb    = (unsigned short*)(ws +  67108864UL);   //  64 MB    +32 MB
  unsigned short* aggb  = (unsigned short*)(ws + 100663296UL);   //  96 MB    +32 MB
  float*          posA  = (float*)(ws + 134217728UL);            // +1 MB (stride-4)
  float*          posB  = (float*)(ws + 135266304UL);            // +1 MB (stride-4)
  float*          g     = (float*)(ws + 136314880UL);            // +2 MB
  float*          h0    = (float*)(ws + 138412032UL);            // +32 KB
  unsigned short* Wt1   = (unsigned short*)(ws + 138444800UL);   // +512 KB (2 layers, frag-order)
  unsigned short* Wut   = (unsigned short*)(ws + 138969088UL);   // +512 KB (2 layers, frag-order)
  int*            deg   = (int*)(ws + 139493376UL);              // +256 KB
  int*            cur   = (int*)(ws + 139755520UL);              // +256 KB
  int*            bsum  = (int*)(ws + 140017664UL);              // +1 KB
  int*            rowptr= (int*)(ws + 140018688UL);              // +256 KB -> ends 140280832
  int*            src_s = (int*)(ws + 140280832UL);              // +1 MB   -> ends 141329408
  float*          Uc    = (float*)(ws + 141329408UL);            // +2.2 MB (2112x256 f32)

  // layer-0 rank-decomposition scratch (region reuse; all stream-ordered):
  //   hg  (1.06 MB bf16)  lives in the aggb region   (dead until edge0 writes aggb)
  //   Xc,Zc (2.1 MB f32)  live in the X / Zb regions (bf16 X/Zb only written in l1)
  unsigned short* hg = aggb;
  float*          Xc = (float*)X;
  float*          Zc = (float*)Zb;

  // ---- stage 1: zero degrees ----
  hipMemsetAsync(deg, 0, (size_t)NN_ * sizeof(int), stream);

  // ---- stage 2: all independent prep in ONE dispatch (deg | wconv | h0 | meand_g) ----
  mega1_kernel<<<3360, 256, 0, stream>>>(ei, deg, Wm, Wu, Wt1, Wut,
                                         x, W_in, b_in, h0,
                                         positions, Wg1, bg1, Wg2, bg2, g);

  // ---- stage 3: scan hierarchy ----
  scan1_kernel<<<256, 256, 0, stream>>>(deg, bsum);
  scan2_kernel<<<1, 256, 0, stream>>>(bsum);

  // ---- stage 4: scan3 | initpack (hbf, hg, pos4) ----
  mega2_kernel<<<8964, 256, 0, stream>>>(deg, bsum, cur, rowptr,
                                         h0, g, positions, hbf, hg, posA);

  // ---- stage 5: scatter | gemm1_small | Uc-small-GEMM ----
  mega3_kernel<<<1090, 256, 0, stream>>>(ei, cur, src_s, hg, Wt1, Wut, bm, Xc, Zc, Uc);

  // ---- layer 0: table-gather edge (4 nodes/wave) + rank-decomposed update GEMM ----
  edge0_kernel<<<NN_ / 16, 256, 0, stream>>>(Xc, Zc, posA, rowptr, src_s,
                                             Wm + 512 * H_, Wp, aggb, posB);
  upd2_dec<<<NN_ / 64, 256, 0, stream>>>(hbf, aggb, Wut + 65536, Uc, bu);

  // ---- layer 1: full path (bf16 X table; pos update dead in final layer) ----
  gemm1_mfma<<<NN_ / 64, 256, 0, stream>>>(hbf, Wt1 + 131072,
                                           bm + H_, X, Zb);
  edge_kernel<<<NN_ / 16, 256, 0, stream>>>(X, Zb, posB, rowptr, src_s,
                                            Wm + (size_t)513 * H_ + 512 * H_,
                                            aggb);
  upd2_out<<<NN_ / 64, 256, 0, stream>>>(hbf, aggb, Wut + 131072,
                                         bu + H_, W_out, b_out, out);
}

// Round 13
// 298.569 us; speedup vs baseline: 1.0147x; 1.0147x over previous
//
#include <hip/hip_runtime.h>
#include <math.h>

#define B_ 32
#define F_ 128
#define H_ 256
#define N_ 2048
#define L_ 2
#define E_ 262144
#define NN_ 65536          // B_*N_
// DEG = E/(B*N) = 4

typedef __attribute__((ext_vector_type(8))) short short8;   // 8 bf16 = 4 VGPRs (MFMA A/B frag)
typedef __attribute__((ext_vector_type(4))) float f32x4;    // MFMA C/D frag
typedef __attribute__((ext_vector_type(2))) float f32x2;    // packed-FP32 pair (v_pk_*_f32)

static __device__ __forceinline__ unsigned short f2bf(float f) {
  unsigned int u = __float_as_uint(f);
  u += 0x7FFF + ((u >> 16) & 1);      // round-to-nearest-even
  return (unsigned short)(u >> 16);
}
static __device__ __forceinline__ float bf2f(unsigned short u) {
  return __uint_as_float(((unsigned int)u) << 16);
}
// 2×f32 -> packed 2×bf16 in one u32 (RNE), single instruction
static __device__ __forceinline__ unsigned int pk_bf16(float lo, float hi) {
  unsigned int r;
  asm("v_cvt_pk_bf16_f32 %0, %1, %2" : "=v"(r) : "v"(lo), "v"(hi));
  return r;
}

// async global->LDS, 16B per lane; LDS dest = wave-uniform base + lane*16
typedef const __attribute__((address_space(1))) unsigned int* as1p;
typedef __attribute__((address_space(3))) unsigned int* as3p;
static __device__ __forceinline__ void gload16(const void* g, void* l) {
  __builtin_amdgcn_global_load_lds((as1p)g, (as3p)l, 16, 0, 0);
}

// ---------------- mega1: deg | wconv | h0 | meand_g (all independent) ----------------
// blocks: [0,1024) deg ; [1024,1280) wconv ; [1280,1312) h0 ; [1312,3360) meand_g
__global__ void mega1_kernel(const int* __restrict__ ei, int* __restrict__ deg,
                             const float* __restrict__ Wm, const float* __restrict__ Wu,
                             unsigned short* __restrict__ Wt1, unsigned short* __restrict__ Wut,
                             const float* __restrict__ x, const float* __restrict__ W_in,
                             const float* __restrict__ b_in, float* __restrict__ h0,
                             const float* __restrict__ positions,
                             const float* __restrict__ Wg1, const float* __restrict__ bg1,
                             const float* __restrict__ Wg2, const float* __restrict__ bg2,
                             float* __restrict__ g) {
  __shared__ float red[256];
  __shared__ float hid[128];
  const int blk = blockIdx.x;
  const int t = threadIdx.x;
  if (blk < 1024) {
    // deg
    int e = blk * 256 + t;
    atomicAdd(&deg[ei[E_ + e]], 1);
  } else if (blk < 1280) {
    // wconv (frag-order weight conversion)
    int idx = (blk - 1024) * 256 + t;            // 0..65535
    int sel = idx >> 14;                          // 0,1: Wm l0,l1 ; 2,3: Wu l0,l1
    int rem = idx & 16383;
    if (sel < 2) {
      const float* W = Wm + (size_t)sel * 513 * H_;
      unsigned short* dst = Wt1 + (size_t)sel * 131072 + ((size_t)rem << 3);
      int gg = rem >> 13;
      int r2 = rem & 8191;
      int kc = r2 >> 11, w = (r2 >> 9) & 3, ks = (r2 >> 8) & 1, ni = (r2 >> 6) & 3, lane = r2 & 63;
      int r = lane & 15, q = lane >> 4;
      int n  = (w << 6) + (ni << 4) + r;
      int kb = (gg << 8) + (kc << 6) + (ks << 5) + (q << 3);
#pragma unroll
      for (int j = 0; j < 8; ++j)
        dst[j] = f2bf(W[(size_t)(kb + j) * H_ + n]);
    } else {
      const float* W = Wu + (size_t)(sel - 2) * 512 * H_;
      unsigned short* dst = Wut + (size_t)(sel - 2) * 131072 + ((size_t)rem << 3);
      int kc = rem >> 11, w = (rem >> 9) & 3, ks = (rem >> 8) & 1, ni = (rem >> 6) & 3, lane = rem & 63;
      int r = lane & 15, q = lane >> 4;
      int n  = (w << 6) + (ni << 4) + r;
      int kb = (kc << 6) + (ks << 5) + (q << 3);
#pragma unroll
      for (int j = 0; j < 8; ++j)
        dst[j] = f2bf(W[(size_t)(kb + j) * H_ + n]);
    }
  } else if (blk < 1312) {
    // h0
    int b = blk - 1280;
    float acc = b_in[t];
#pragma unroll 8
    for (int k = 0; k < F_; ++k)
      acc += x[b * F_ + k] * W_in[k * H_ + t];
    h0[b * H_ + t] = acc;
  } else {
    // meand_g: one block per node n
    int n = blk - 1312;
    float px = positions[n * 3 + 0], py = positions[n * 3 + 1], pz = positions[n * 3 + 2];
    float s = 0.f;
    for (int j = t; j < N_; j += 256) {
      float dx = px - positions[j * 3 + 0];
      float dy = py - positions[j * 3 + 1];
      float dz = pz - positions[j * 3 + 2];
      s += sqrtf(dx * dx + dy * dy + dz * dz);
    }
    red[t] = s;
    __syncthreads();
    for (int off = 128; off > 0; off >>= 1) {
      if (t < off) red[t] += red[t + off];
      __syncthreads();
    }
    float md = red[0] / (float)(N_ - 1);
    if (t < 128) {
      float w = Wg1[t] + Wg1[128 + t] + Wg1[256 + t];
      hid[t] = fmaxf(md * w + bg1[t], 0.f);
    }
    __syncthreads();
    float acc = bg2[t];
#pragma unroll 8
    for (int k = 0; k < 128; ++k)
      acc += hid[k] * Wg2[k * H_ + t];
    g[n * H_ + t] = acc;
  }
}

// ---------------- CSR scans (unchanged, small) ----------------

__global__ void scan1_kernel(const int* __restrict__ deg, int* __restrict__ bsum) {
  __shared__ int red[256];
  int t = threadIdx.x;
  red[t] = deg[blockIdx.x * 256 + t];
  __syncthreads();
  for (int off = 128; off > 0; off >>= 1) {
    if (t < off) red[t] += red[t + off];
    __syncthreads();
  }
  if (t == 0) bsum[blockIdx.x] = red[0];
}

__global__ void scan2_kernel(int* __restrict__ bsum) {
  __shared__ int s[256];
  int t = threadIdx.x;
  s[t] = bsum[t];
  __syncthreads();
  for (int off = 1; off < 256; off <<= 1) {
    int v = (t >= off) ? s[t - off] : 0;
    __syncthreads();
    s[t] += v;
    __syncthreads();
  }
  bsum[t] = (t == 0) ? 0 : s[t - 1];
}

// ---------------- mega2: scan3 | initpack ----------------
// blocks [0,256): scan3 ; [256, 8964): initpack
__global__ void mega2_kernel(const int* __restrict__ deg, const int* __restrict__ bsum,
                             int* __restrict__ cur, int* __restrict__ rowptr,
                             const float* __restrict__ h0, const float* __restrict__ g,
                             const float* __restrict__ positions,
                             unsigned short* __restrict__ hbf,
                             unsigned short* __restrict__ hg,
                             float* __restrict__ pos4) {
  __shared__ int s[256];
  const int blk0 = blockIdx.x;
  const int t = threadIdx.x;
  if (blk0 < 256) {
    // scan3: writes BOTH cur and rowptr
    int i = blk0 * 256 + t;
    s[t] = deg[i];
    __syncthreads();
    for (int off = 1; off < 256; off <<= 1) {
      int v = (t >= off) ? s[t - off] : 0;
      __syncthreads();
      s[t] += v;
      __syncthreads();
    }
    int excl = (t == 0) ? 0 : s[t - 1];
    int v = bsum[blk0] + excl;
    cur[i] = v;
    rowptr[i] = v;
    return;
  }
  const int blk = blk0 - 256;
  if (blk < 8192) {
    int idx = blk * 256 + t;  // NN*32, 8 ch each
    int row = idx >> 5;
    int c8 = (idx & 31) << 3;
    const float* hp = h0 + (row >> 11) * H_ + c8;
    const float* gp = g + (row & (N_ - 1)) * H_ + c8;
    const float4 a = *(const float4*)hp;
    const float4 a2 = *(const float4*)(hp + 4);
    const float4 b = *(const float4*)gp;
    const float4 b2 = *(const float4*)(gp + 4);
    short8 v;
    v[0] = (short)f2bf(a.x + b.x);  v[1] = (short)f2bf(a.y + b.y);
    v[2] = (short)f2bf(a.z + b.z);  v[3] = (short)f2bf(a.w + b.w);
    v[4] = (short)f2bf(a2.x + b2.x); v[5] = (short)f2bf(a2.y + b2.y);
    v[6] = (short)f2bf(a2.z + b2.z); v[7] = (short)f2bf(a2.w + b2.w);
    *(short8*)(hbf + (((size_t)row) << 8) + c8) = v;
  } else if (blk < 8452) {
    int idx = (blk - 8192) * 256 + t;  // 2080*32, 8 ch each
    int row = idx >> 5;
    int c8 = (idx & 31) << 3;
    const float* src = (row < 2048) ? (g + (size_t)row * H_ + c8)
                                    : (h0 + (size_t)(row - 2048) * H_ + c8);
    const float4 a = *(const float4*)src;
    const float4 a2 = *(const float4*)(src + 4);
    short8 v;
    v[0] = (short)f2bf(a.x);  v[1] = (short)f2bf(a.y);
    v[2] = (short)f2bf(a.z);  v[3] = (short)f2bf(a.w);
    v[4] = (short)f2bf(a2.x); v[5] = (short)f2bf(a2.y);
    v[6] = (short)f2bf(a2.z); v[7] = (short)f2bf(a2.w);
    *(short8*)(hg + (((size_t)row) << 8) + c8) = v;
  } else {
    int n = (blk - 8452) * 256 + t;   // 0..NN-1
    int src = (n & (N_ - 1)) * 3;
    float4 v;
    v.x = positions[src + 0];
    v.y = positions[src + 1];
    v.z = positions[src + 2];
    v.w = 0.f;
    *(float4*)(pos4 + ((size_t)n << 2)) = v;
  }
}

// ============ counted-vmcnt pipelined GEMM (K=32 phases, 4 buffers, depth-3) ============
// (round-5 proven structure)

#define GEMM_IDS(BID)                                                \
  const int t = threadIdx.x;                                         \
  const int m0 = (BID) << 6;                                         \
  const int wu = __builtin_amdgcn_readfirstlane(t >> 6);             \
  const int lane = t & 63;                                           \
  const int q = lane >> 4;                                           \
  const int r = lane & 15;                                           \
  const int arow = lane >> 2;                                        \
  const int aq = (lane & 3) ^ ((lane >> 2) & 3);   /* pre-swizzled src quad */

#define STAGE_P(P, abase)                                                                \
  do {                                                                                   \
    gload16((abase) + (((size_t)(m0 + (wu << 4) + arow)) << 8) + (((P) & 7) << 5) +      \
                (aq << 3),                                                               \
            &sA[(P) & 3][wu << 9]);                                                      \
    _Pragma("unroll")                                                                    \
    for (int j_ = 0; j_ < 4; ++j_)                                                       \
      gload16(Wt + (((size_t)((P) >> 1)) << 14) + (wu << 12) + (((P) & 1) << 11) +       \
                  (j_ << 9) + (lane << 3),                                               \
              &sB[(P) & 3][(wu << 11) + (j_ << 9)]);                                     \
  } while (0)

#define COMPUTE_P(P)                                                                     \
  do {                                                                                   \
    short8 af[4], bfr[4];                                                                \
    _Pragma("unroll")                                                                    \
    for (int mi = 0; mi < 4; ++mi)                                                       \
      af[mi] = *(const short8*)(&sA[(P) & 3][((mi * 16 + r) << 5) +                      \
                                             ((q ^ (r & 3)) << 3)]);                     \
    _Pragma("unroll")                                                                    \
    for (int ni = 0; ni < 4; ++ni)                                                       \
      bfr[ni] = *(const short8*)(&sB[(P) & 3][(wu << 11) + (ni << 9) + (lane << 3)]);    \
    _Pragma("unroll")                                                                    \
    for (int mi = 0; mi < 4; ++mi)                                                       \
      _Pragma("unroll")                                                                  \
      for (int ni = 0; ni < 4; ++ni)                                                     \
        acc[mi][ni] = __builtin_amdgcn_mfma_f32_16x16x32_bf16(af[mi], bfr[ni],           \
                                                              acc[mi][ni], 0, 0, 0);     \
  } while (0)

// 16-phase wait schedule
#define WAIT_BAR(P)                                                       \
  do {                                                                    \
    if ((P) <= 13)      asm volatile("s_waitcnt vmcnt(10)" ::: "memory"); \
    else if ((P) == 14) asm volatile("s_waitcnt vmcnt(5)" ::: "memory");  \
    else                asm volatile("s_waitcnt vmcnt(0)" ::: "memory");  \
    __builtin_amdgcn_s_barrier();                                         \
    asm volatile("" ::: "memory");                                        \
  } while (0)

// 8-phase wait schedule
#define WAIT_BAR8(P)                                                      \
  do {                                                                    \
    if ((P) <= 5)       asm volatile("s_waitcnt vmcnt(10)" ::: "memory"); \
    else if ((P) == 6)  asm volatile("s_waitcnt vmcnt(5)" ::: "memory");  \
    else                asm volatile("s_waitcnt vmcnt(0)" ::: "memory");  \
    __builtin_amdgcn_s_barrier();                                         \
    asm volatile("" ::: "memory");                                        \
  } while (0)

#define ACC_ZERO()                                   \
  _Pragma("unroll")                                  \
  for (int mi = 0; mi < 4; ++mi)                     \
    _Pragma("unroll")                                \
    for (int ni = 0; ni < 4; ++ni)                   \
      acc[mi][ni] = (f32x4){0.f, 0.f, 0.f, 0.f};

// ---------------- mega3: scatter | gemm1_small | Uc-small-GEMM ----------------
// blocks [0,1024): scatter ; [1024,1057): gemm1_small (Wm l0, 16 phases)
// [1057,1090): Uc GEMM  (hg @ Wu_l0[0:256,:] -> Uc, 8 phases)
__launch_bounds__(256)
__global__ void mega3_kernel(const int* __restrict__ ei, int* __restrict__ cur,
                             int* __restrict__ src_s,
                             const unsigned short* __restrict__ hg,
                             const unsigned short* __restrict__ Wtm,   // Wm layer0 frag
                             const unsigned short* __restrict__ Wtu,   // Wu layer0 frag
                             const float* __restrict__ bm,
                             float* __restrict__ Xc, float* __restrict__ Zc,
                             float* __restrict__ Uc) {
  __shared__ __align__(16) unsigned short sA[4][2048];
  __shared__ __align__(16) unsigned short sB[4][8192];
  const int blk = blockIdx.x;
  if (blk < 1024) {
    // scatter
    int e = blk * 256 + threadIdx.x;
    int s = ei[e], d = ei[E_ + e];
    int p = atomicAdd(&cur[d], 1);
    src_s[p] = s;
    return;
  }
  if (blk < 1057) {
    // gemm1_small: layer-0 rank decomposition (2112 rows, f32 out), K=512 of Wm
    const int bid = blk - 1024;
    const unsigned short* Wt = Wtm;
    GEMM_IDS(bid)

    f32x4 acc[4][4];
    ACC_ZERO();

    STAGE_P(0, hg); STAGE_P(1, hg); STAGE_P(2, hg);
#pragma unroll
    for (int p = 0; p < 16; ++p) {
      WAIT_BAR(p);
      if (p + 3 < 16) STAGE_P(p + 3, hg);
      COMPUTE_P(p);
      if (p == 7) {
#pragma unroll
        for (int ni = 0; ni < 4; ++ni) {
          int n = (wu << 6) + ni * 16 + r;
#pragma unroll
          for (int mi = 0; mi < 4; ++mi)
#pragma unroll
            for (int reg = 0; reg < 4; ++reg) {
              size_t idx = (((size_t)(m0 + mi * 16 + q * 4 + reg)) << 8) + n;
              Xc[idx] = acc[mi][ni][reg];
              acc[mi][ni][reg] = 0.f;
            }
        }
      }
    }

    const int isH0 = (bid == 32);   // rows 2048.. carry h0 -> bias lives here
#pragma unroll
    for (int ni = 0; ni < 4; ++ni) {
      int n = (wu << 6) + ni * 16 + r;
      float bmn = isH0 ? bm[n] : 0.f;
#pragma unroll
      for (int mi = 0; mi < 4; ++mi)
#pragma unroll
        for (int reg = 0; reg < 4; ++reg) {
          size_t idx = (((size_t)(m0 + mi * 16 + q * 4 + reg)) << 8) + n;
          Zc[idx] = acc[mi][ni][reg] + bmn;
        }
    }
    return;
  }
  // Uc GEMM: hg @ Wu_l0 rows 0..255 (pieces 0..3), 8 phases, f32 out (no bias)
  {
    const int bid = blk - 1057;
    const unsigned short* Wt = Wtu;
    GEMM_IDS(bid)

    f32x4 acc[4][4];
    ACC_ZERO();

    STAGE_P(0, hg); STAGE_P(1, hg); STAGE_P(2, hg);
#pragma unroll
    for (int p = 0; p < 8; ++p) {
      WAIT_BAR8(p);
      if (p + 3 < 8) STAGE_P(p + 3, hg);
      COMPUTE_P(p);
    }
#pragma unroll
    for (int ni = 0; ni < 4; ++ni) {
      int n = (wu << 6) + ni * 16 + r;
#pragma unroll
      for (int mi = 0; mi < 4; ++mi)
#pragma unroll
        for (int reg = 0; reg < 4; ++reg) {
          size_t idx = (((size_t)(m0 + mi * 16 + q * 4 + reg)) << 8) + n;
          Uc[idx] = acc[mi][ni][reg];
        }
    }
  }
}

// ---------------- GEMM1: 16 phases (p0-7: g=0 -> X bf16, p8-15: g=1 -> Zb bf16) ----------------
__launch_bounds__(256)
__global__ void gemm1_mfma(const unsigned short* __restrict__ hbf,
                           const unsigned short* __restrict__ Wt,
                           const float* __restrict__ bm,
                           unsigned short* __restrict__ X, unsigned short* __restrict__ Zb) {
  __shared__ __align__(16) unsigned short sA[4][2048];
  __shared__ __align__(16) unsigned short sB[4][8192];
  GEMM_IDS(blockIdx.x)

  f32x4 acc[4][4];
  ACC_ZERO();

  STAGE_P(0, hbf); STAGE_P(1, hbf); STAGE_P(2, hbf);
#pragma unroll
  for (int p = 0; p < 16; ++p) {
    WAIT_BAR(p);
    if (p + 3 < 16) STAGE_P(p + 3, hbf);
    COMPUTE_P(p);
    if (p == 7) {
      // g=0 half done: store X, reset acc
#pragma unroll
      for (int ni = 0; ni < 4; ++ni) {
        int n = (wu << 6) + ni * 16 + r;
#pragma unroll
        for (int mi = 0; mi < 4; ++mi)
#pragma unroll
          for (int reg = 0; reg < 4; ++reg) {
            size_t idx = (((size_t)(m0 + mi * 16 + q * 4 + reg)) << 8) + n;
            X[idx] = f2bf(acc[mi][ni][reg]);
            acc[mi][ni][reg] = 0.f;
          }
      }
    }
  }

  // g=1 half: store Zb (+bm)
#pragma unroll
  for (int ni = 0; ni < 4; ++ni) {
    int n = (wu << 6) + ni * 16 + r;
    float bmn = bm[n];
#pragma unroll
    for (int mi = 0; mi < 4; ++mi)
#pragma unroll
      for (int reg = 0; reg < 4; ++reg) {
        size_t idx = (((size_t)(m0 + mi * 16 + q * 4 + reg)) << 8) + n;
        Zb[idx] = f2bf(acc[mi][ni][reg] + bmn);
      }
  }
}

// ---------------- edge kernels: round-11 proven (1 node/wave, scalar CSR, 4-wide groups) ----------------
static __device__ __forceinline__ void edge_core(
    const float4 pn, const float4 q,
    f32x2 x01, f32x2 x23,
    const f32x2 z01, const f32x2 z23,
    const f32x2 wl01, const f32x2 wl23,
    const f32x2 wp01, const f32x2 wp23,
    f32x2& a01, f32x2& a23,
    float& pdx, float& pdy, float& pdz) {
  const float dx = pn.x - q.x, dy = pn.y - q.y, dz = pn.z - q.z;
  const float d = sqrtf(dx * dx + dy * dy + dz * dz + 1e-12f);
  f32x2 dd; dd[0] = d; dd[1] = d;
  f32x2 v01 = x01 + z01 + dd * wl01;          // v_pk_add + v_pk_fma
  f32x2 v23 = x23 + z23 + dd * wl23;
  v01[0] = fmaxf(v01[0], 0.f); v01[1] = fmaxf(v01[1], 0.f);
  v23[0] = fmaxf(v23[0], 0.f); v23[1] = fmaxf(v23[1], 0.f);
  a01 += v01; a23 += v23;
  const f32x2 cpv = v01 * wp01 + v23 * wp23;  // v_pk_mul + v_pk_fma
  const float cp = cpv[0] + cpv[1];
  pdx += dx * cp; pdy += dy * cp; pdz += dz * cp;
}

// no-pos variant: final-layer position update is dead code in the reference
static __device__ __forceinline__ void edge_core_np(
    const float4 pn, const float4 q,
    f32x2 x01, f32x2 x23,
    const f32x2 z01, const f32x2 z23,
    const f32x2 wl01, const f32x2 wl23,
    f32x2& a01, f32x2& a23) {
  const float dx = pn.x - q.x, dy = pn.y - q.y, dz = pn.z - q.z;
  const float d = sqrtf(dx * dx + dy * dy + dz * dz + 1e-12f);
  f32x2 dd; dd[0] = d; dd[1] = d;
  f32x2 v01 = x01 + z01 + dd * wl01;
  f32x2 v23 = x23 + z23 + dd * wl23;
  v01[0] = fmaxf(v01[0], 0.f); v01[1] = fmaxf(v01[1], 0.f);
  v23[0] = fmaxf(v23[0], 0.f); v23[1] = fmaxf(v23[1], 0.f);
  a01 += v01; a23 += v23;
}

static __device__ __forceinline__ void edge_do_np(
    const float4 pn, const float4 q, const uint2 xv,
    const f32x2 z01, const f32x2 z23,
    const f32x2 wl01, const f32x2 wl23,
    f32x2& a01, f32x2& a23) {
  f32x2 x01, x23;
  x01[0] = __uint_as_float(xv.x << 16);
  x01[1] = __uint_as_float(xv.x & 0xffff0000u);
  x23[0] = __uint_as_float(xv.y << 16);
  x23[1] = __uint_as_float(xv.y & 0xffff0000u);
  edge_core_np(pn, q, x01, x23, z01, z23, wl01, wl23, a01, a23);
}

static __device__ __forceinline__ void edge_do0(
    const float4 pn, const float4 q, const float4 xg, const float4 xh,
    const f32x2 z01, const f32x2 z23,
    const f32x2 wl01, const f32x2 wl23,
    const f32x2 wp01, const f32x2 wp23,
    f32x2& a01, f32x2& a23,
    float& pdx, float& pdy, float& pdz) {
  f32x2 x01, x23;
  x01[0] = xg.x + xh.x; x01[1] = xg.y + xh.y;
  x23[0] = xg.z + xh.z; x23[1] = xg.w + xh.w;
  edge_core(pn, q, x01, x23, z01, z23, wl01, wl23, wp01, wp23, a01, a23, pdx, pdy, pdz);
}

// layer-1 edge (FINAL layer): pos/coef path removed — dead in reference.
__launch_bounds__(256)
__global__ void edge_kernel(const unsigned short* __restrict__ X,
                            const unsigned short* __restrict__ Zb,
                            const float* __restrict__ pos_c,   // stride-4
                            const int* __restrict__ rowptr, const int* __restrict__ src_s,
                            const float* __restrict__ wl,
                            unsigned short* __restrict__ aggb) {
  const int gid = blockIdx.x * 256 + threadIdx.x;
  // n is wave-uniform; force SGPR so the CSR walk is scalar.
  const int n = __builtin_amdgcn_readfirstlane(gid >> 6);
  const int lane = threadIdx.x & 63;

  const float4 wlv = *(const float4*)(wl + (lane << 2));
  const f32x2 wl01 = {wlv.x, wlv.y}, wl23 = {wlv.z, wlv.w};

  const int e0 = rowptr[n];
  const int e1 = (n == NN_ - 1) ? E_ : rowptr[n + 1];

  const uint2 zv = *(const uint2*)(Zb + (((size_t)n) << 8) + (lane << 2));
  f32x2 z01, z23;
  z01[0] = __uint_as_float(zv.x << 16);
  z01[1] = __uint_as_float(zv.x & 0xffff0000u);
  z23[0] = __uint_as_float(zv.y << 16);
  z23[1] = __uint_as_float(zv.y & 0xffff0000u);

  const float4 pn = *(const float4*)(pos_c + ((size_t)n << 2));
  f32x2 a01 = {0.f, 0.f}, a23 = {0.f, 0.f};

  const unsigned short* Xl = X + (lane << 2);

  int e = e0;
  for (; e + 4 <= e1; e += 4) {
    const int s0 = src_s[e], s1 = src_s[e + 1], s2 = src_s[e + 2], s3 = src_s[e + 3];
    const float4 q0 = *(const float4*)(pos_c + ((size_t)s0 << 2));
    const float4 q1 = *(const float4*)(pos_c + ((size_t)s1 << 2));
    const float4 q2 = *(const float4*)(pos_c + ((size_t)s2 << 2));
    const float4 q3 = *(const float4*)(pos_c + ((size_t)s3 << 2));
    const uint2 x0 = *(const uint2*)(Xl + (((size_t)s0) << 8));
    const uint2 x1 = *(const uint2*)(Xl + (((size_t)s1) << 8));
    const uint2 x2 = *(const uint2*)(Xl + (((size_t)s2) << 8));
    const uint2 x3 = *(const uint2*)(Xl + (((size_t)s3) << 8));
    edge_do_np(pn, q0, x0, z01, z23, wl01, wl23, a01, a23);
    edge_do_np(pn, q1, x1, z01, z23, wl01, wl23, a01, a23);
    edge_do_np(pn, q2, x2, z01, z23, wl01, wl23, a01, a23);
    edge_do_np(pn, q3, x3, z01, z23, wl01, wl23, a01, a23);
  }
  if (e + 2 <= e1) {
    const int s0 = src_s[e], s1 = src_s[e + 1];
    const float4 q0 = *(const float4*)(pos_c + ((size_t)s0 << 2));
    const float4 q1 = *(const float4*)(pos_c + ((size_t)s1 << 2));
    const uint2 x0 = *(const uint2*)(Xl + (((size_t)s0) << 8));
    const uint2 x1 = *(const uint2*)(Xl + (((size_t)s1) << 8));
    edge_do_np(pn, q0, x0, z01, z23, wl01, wl23, a01, a23);
    edge_do_np(pn, q1, x1, z01, z23, wl01, wl23, a01, a23);
    e += 2;
  }
  if (e < e1) {
    const int s0 = src_s[e];
    const float4 q0 = *(const float4*)(pos_c + ((size_t)s0 << 2));
    const uint2 x0 = *(const uint2*)(Xl + (((size_t)s0) << 8));
    edge_do_np(pn, q0, x0, z01, z23, wl01, wl23, a01, a23);
  }

  uint2 av;
  av.x = pk_bf16(a01[0], a01[1]);
  av.y = pk_bf16(a23[0], a23[1]);
  *(uint2*)(aggb + (((size_t)n) << 8) + (lane << 2)) = av;
}

// layer-0 edge: X/Z from rank-decomposed f32 tables Xc/Zc (2112 rows; L2-hot)
__launch_bounds__(256)
__global__ void edge0_kernel(const float* __restrict__ Xc,
                             const float* __restrict__ Zc,
                             const float* __restrict__ pos_c,   // stride-4
                             const int* __restrict__ rowptr, const int* __restrict__ src_s,
                             const float* __restrict__ wl, const float* __restrict__ wp,
                             unsigned short* __restrict__ aggb, float* __restrict__ pos_o) {
  const int gid = blockIdx.x * 256 + threadIdx.x;
  const int n = __builtin_amdgcn_readfirstlane(gid >> 6);
  const int lane = threadIdx.x & 63;

  const float4 wlv = *(const float4*)(wl + (lane << 2));
  const float4 wpv = *(const float4*)(wp + (lane << 2));
  const f32x2 wl01 = {wlv.x, wlv.y}, wl23 = {wlv.z, wlv.w};
  const f32x2 wp01 = {wpv.x, wpv.y}, wp23 = {wpv.z, wpv.w};

  const int e0 = rowptr[n];
  const int e1 = (n == NN_ - 1) ? E_ : rowptr[n + 1];

  const float* Xl = Xc + (lane << 2);
  const float* Zl = Zc + (lane << 2);

  // z = Zg[node] + Zh0[batch] (Zh0 carries bm)
  const float4 zg = *(const float4*)(Zl + (((size_t)(n & (N_ - 1))) << 8));
  const float4 zh = *(const float4*)(Zl + (((size_t)(2048 + (n >> 11))) << 8));
  f32x2 z01, z23;
  z01[0] = zg.x + zh.x; z01[1] = zg.y + zh.y;
  z23[0] = zg.z + zh.z; z23[1] = zg.w + zh.w;

  const float4 pn = *(const float4*)(pos_c + ((size_t)n << 2));
  f32x2 a01 = {0.f, 0.f}, a23 = {0.f, 0.f};
  float pdx = 0.f, pdy = 0.f, pdz = 0.f;

  int e = e0;
  for (; e + 4 <= e1; e += 4) {
    const int s0 = src_s[e], s1 = src_s[e + 1], s2 = src_s[e + 2], s3 = src_s[e + 3];
    const float4 q0 = *(const float4*)(pos_c + ((size_t)s0 << 2));
    const float4 q1 = *(const float4*)(pos_c + ((size_t)s1 << 2));
    const float4 q2 = *(const float4*)(pos_c + ((size_t)s2 << 2));
    const float4 q3 = *(const float4*)(pos_c + ((size_t)s3 << 2));
    const float4 xg0 = *(const float4*)(Xl + (((size_t)(s0 & (N_ - 1))) << 8));
    const float4 xh0 = *(const float4*)(Xl + (((size_t)(2048 + (s0 >> 11))) << 8));
    const float4 xg1 = *(const float4*)(Xl + (((size_t)(s1 & (N_ - 1))) << 8));
    const float4 xh1 = *(const float4*)(Xl + (((size_t)(2048 + (s1 >> 11))) << 8));
    const float4 xg2 = *(const float4*)(Xl + (((size_t)(s2 & (N_ - 1))) << 8));
    const float4 xh2 = *(const float4*)(Xl + (((size_t)(2048 + (s2 >> 11))) << 8));
    const float4 xg3 = *(const float4*)(Xl + (((size_t)(s3 & (N_ - 1))) << 8));
    const float4 xh3 = *(const float4*)(Xl + (((size_t)(2048 + (s3 >> 11))) << 8));
    edge_do0(pn, q0, xg0, xh0, z01, z23, wl01, wl23, wp01, wp23, a01, a23, pdx, pdy, pdz);
    edge_do0(pn, q1, xg1, xh1, z01, z23, wl01, wl23, wp01, wp23, a01, a23, pdx, pdy, pdz);
    edge_do0(pn, q2, xg2, xh2, z01, z23, wl01, wl23, wp01, wp23, a01, a23, pdx, pdy, pdz);
    edge_do0(pn, q3, xg3, xh3, z01, z23, wl01, wl23, wp01, wp23, a01, a23, pdx, pdy, pdz);
  }
  for (; e < e1; ++e) {
    const int s0 = src_s[e];
    const float4 q0 = *(const float4*)(pos_c + ((size_t)s0 << 2));
    const float4 xg0 = *(const float4*)(Xl + (((size_t)(s0 & (N_ - 1))) << 8));
    const float4 xh0 = *(const float4*)(Xl + (((size_t)(2048 + (s0 >> 11))) << 8));
    edge_do0(pn, q0, xg0, xh0, z01, z23, wl01, wl23, wp01, wp23, a01, a23, pdx, pdy, pdz);
  }

  uint2 av;
  av.x = pk_bf16(a01[0], a01[1]);
  av.y = pk_bf16(a23[0], a23[1]);
  *(uint2*)(aggb + (((size_t)n) << 8) + (lane << 2)) = av;

#pragma unroll
  for (int m = 1; m < 64; m <<= 1) {
    pdx += __shfl_xor(pdx, m, 64);
    pdy += __shfl_xor(pdy, m, 64);
    pdz += __shfl_xor(pdz, m, 64);
  }
  if (lane == 0) {
    float4 po;
    po.x = pn.x + pdx * 0.25f;
    po.y = pn.y + pdy * 0.25f;
    po.z = pn.z + pdz * 0.25f;
    po.w = 0.f;
    *(float4*)(pos_o + ((size_t)n << 2)) = po;
  }
}

// ---------------- GEMM2 layer-0: rank-decomposed hbf half (acc init from Uc) ----------------
// acc = Uc[g-part] + Uc[h0-part]  (K=0..255 contribution), then 8 phases over aggb (K=256..511).
// Wt must point at Wu-layer0 frag pieces 4..7 (i.e. Wut + 65536).
__launch_bounds__(256)
__global__ void upd2_dec(unsigned short* __restrict__ hbf,
                         const unsigned short* __restrict__ aggb,
                         const unsigned short* __restrict__ Wt,
                         const float* __restrict__ Uc,
                         const float* __restrict__ bu) {
  __shared__ __align__(16) unsigned short sA[4][2048];
  __shared__ __align__(16) unsigned short sB[4][8192];
  GEMM_IDS(blockIdx.x)

  const int nn0 = m0 & (N_ - 1);   // block's 64 rows share one batch (64 | 2048)
  const int bb  = m0 >> 11;

  f32x4 acc[4][4];
  // acc init from Uc: 64 consecutive g-rows + one block-uniform h0 row.
#pragma unroll
  for (int ni = 0; ni < 4; ++ni) {
    int n = (wu << 6) + ni * 16 + r;
    float uh = Uc[(((size_t)(2048 + bb)) << 8) + n];
#pragma unroll
    for (int mi = 0; mi < 4; ++mi)
#pragma unroll
      for (int reg = 0; reg < 4; ++reg) {
        int rl = mi * 16 + q * 4 + reg;
        acc[mi][ni][reg] = Uc[(((size_t)(nn0 + rl)) << 8) + n] + uh;
      }
  }

  STAGE_P(0, aggb); STAGE_P(1, aggb); STAGE_P(2, aggb);
#pragma unroll
  for (int p = 0; p < 8; ++p) {
    WAIT_BAR8(p);
    if (p + 3 < 8) STAGE_P(p + 3, aggb);
    COMPUTE_P(p);
  }

  // epilogue: residual add; hbf rows are L2-hot
#pragma unroll
  for (int ni = 0; ni < 4; ++ni) {
    int n = (wu << 6) + ni * 16 + r;
    float buv = bu[n];
#pragma unroll
    for (int mi = 0; mi < 4; ++mi)
#pragma unroll
      for (int reg = 0; reg < 4; ++reg) {
        size_t idx = (((size_t)(m0 + mi * 16 + q * 4 + reg)) << 8) + n;
        float v = bf2f(hbf[idx]) + fmaxf(acc[mi][ni][reg] + buv, 0.f);
        hbf[idx] = f2bf(v);
      }
  }
}

// ---------------- GEMM2 final layer with fused W_out projection ----------------
__launch_bounds__(256)
__global__ void upd2_out(const unsigned short* __restrict__ hbf,
                         const unsigned short* __restrict__ aggb,
                         const unsigned short* __restrict__ Wt,
                         const float* __restrict__ bu,
                         const float* __restrict__ Wout, const float* __restrict__ bout,
                         float* __restrict__ out) {
  __shared__ __align__(16) unsigned short sA[4][2048];
  __shared__ __align__(16) unsigned short sB[4][8192];
  GEMM_IDS(blockIdx.x)

  f32x4 acc[4][4];
  ACC_ZERO();

  STAGE_P(0, hbf); STAGE_P(1, hbf); STAGE_P(2, hbf);
#pragma unroll
  for (int p = 0; p < 16; ++p) {
    WAIT_BAR(p);
    if (p + 3 < 16) {
      const unsigned short* ab = (p + 3 < 8) ? hbf : aggb;
      STAGE_P(p + 3, ab);
    }
    COMPUTE_P(p);
  }
  __syncthreads();                      // LDS reads done; safe to reuse sA for sRed
  float (*sRed)[64] = (float(*)[64])(&sA[0][0]);

  float dotp[4][4];
#pragma unroll
  for (int mi = 0; mi < 4; ++mi)
#pragma unroll
    for (int reg = 0; reg < 4; ++reg)
      dotp[mi][reg] = 0.f;

#pragma unroll
  for (int ni = 0; ni < 4; ++ni) {
    int n = (wu << 6) + ni * 16 + r;
    float buv = bu[n];
    float won = Wout[n];
#pragma unroll
    for (int mi = 0; mi < 4; ++mi)
#pragma unroll
      for (int reg = 0; reg < 4; ++reg) {
        size_t idx = (((size_t)(m0 + mi * 16 + q * 4 + reg)) << 8) + n;
        float v = bf2f(hbf[idx]) + fmaxf(acc[mi][ni][reg] + buv, 0.f);
        dotp[mi][reg] += v * won;
      }
  }
#pragma unroll
  for (int mask = 1; mask < 16; mask <<= 1)
#pragma unroll
    for (int mi = 0; mi < 4; ++mi)
#pragma unroll
      for (int reg = 0; reg < 4; ++reg)
        dotp[mi][reg] += __shfl_xor(dotp[mi][reg], mask, 64);
  if (r == 0) {
#pragma unroll
    for (int mi = 0; mi < 4; ++mi)
#pragma unroll
      for (int reg = 0; reg < 4; ++reg)
        sRed[wu][mi * 16 + q * 4 + reg] = dotp[mi][reg];
  }
  __syncthreads();
  if (t < 64)
    out[m0 + t] = sRed[0][t] + sRed[1][t] + sRed[2][t] + sRed[3][t] + bout[0];
}

// ---------------- launcher ----------------

extern "C" void kernel_launch(void* const* d_in, const int* in_sizes, int n_in,
                              void* d_out, int out_size, void* d_ws, size_t ws_size,
                              hipStream_t stream) {
  const float* x         = (const float*)d_in[0];
  const float* positions = (const float*)d_in[1];
  const float* W_in      = (const float*)d_in[2];
  const float* b_in      = (const float*)d_in[3];
  const float* Wg1       = (const float*)d_in[4];
  const float* bg1       = (const float*)d_in[5];
  const float* Wg2       = (const float*)d_in[6];
  const float* bg2       = (const float*)d_in[7];
  const float* Wm        = (const float*)d_in[8];
  const float* bm        = (const float*)d_in[9];
  const float* Wu        = (const float*)d_in[10];
  const float* bu        = (const float*)d_in[11];
  const float* Wp        = (const float*)d_in[12];
  const float* W_out     = (const float*)d_in[13];
  const float* b_out     = (const float*)d_in[14];
  const int*   ei        = (const int*)d_in[15];
  float* out = (float*)d_out;

  // workspace layout — sequential, non-overlapping (pos stride-4: 1 MB each)
  char* ws = (char*)d_ws;
  unsigned short* hbf   = (unsigned short*)(ws);                 //   0       +32 MB
  unsigned short* X     = (unsigned short*)(ws +  33554432UL);   //  32 MB    +32 MB
  unsigned short* Zb    = (unsigned short*)(ws +  67108864UL);   //  64 MB    +32 MB
  unsigned short* aggb  = (unsigned short*)(ws + 100663296UL);   //  96 MB    +32 MB
  float*          posA  = (float*)(ws + 134217728UL);            // +1 MB (stride-4)
  float*          posB  = (float*)(ws + 135266304UL);            // +1 MB (stride-4)
  float*          g     = (float*)(ws + 136314880UL);            // +2 MB
  float*          h0    = (float*)(ws + 138412032UL);            // +32 KB
  unsigned short* Wt1   = (unsigned short*)(ws + 138444800UL);   // +512 KB (2 layers, frag-order)
  unsigned short* Wut   = (unsigned short*)(ws + 138969088UL);   // +512 KB (2 layers, frag-order)
  int*            deg   = (int*)(ws + 139493376UL);              // +256 KB
  int*            cur   = (int*)(ws + 139755520UL);              // +256 KB
  int*            bsum  = (int*)(ws + 140017664UL);              // +1 KB
  int*            rowptr= (int*)(ws + 140018688UL);              // +256 KB -> ends 140280832
  int*            src_s = (int*)(ws + 140280832UL);              // +1 MB   -> ends 141329408
  float*          Uc    = (float*)(ws + 141329408UL);            // +2.2 MB (2112x256 f32)

  // layer-0 rank-decomposition scratch (region reuse; all stream-ordered):
  //   hg  (1.06 MB bf16)  lives in the aggb region   (dead until edge0 writes aggb)
  //   Xc,Zc (2.1 MB f32)  live in the X / Zb regions (bf16 X/Zb only written in l1)
  unsigned short* hg = aggb;
  float*          Xc = (float*)X;
  float*          Zc = (float*)Zb;

  // ---- stage 1: zero degrees ----
  hipMemsetAsync(deg, 0, (size_t)NN_ * sizeof(int), stream);

  // ---- stage 2: all independent prep in ONE dispatch (deg | wconv | h0 | meand_g) ----
  mega1_kernel<<<3360, 256, 0, stream>>>(ei, deg, Wm, Wu, Wt1, Wut,
                                         x, W_in, b_in, h0,
                                         positions, Wg1, bg1, Wg2, bg2, g);

  // ---- stage 3: scan hierarchy ----
  scan1_kernel<<<256, 256, 0, stream>>>(deg, bsum);
  scan2_kernel<<<1, 256, 0, stream>>>(bsum);

  // ---- stage 4: scan3 | initpack (hbf, hg, pos4) ----
  mega2_kernel<<<8964, 256, 0, stream>>>(deg, bsum, cur, rowptr,
                                         h0, g, positions, hbf, hg, posA);

  // ---- stage 5: scatter | gemm1_small | Uc-small-GEMM ----
  mega3_kernel<<<1090, 256, 0, stream>>>(ei, cur, src_s, hg, Wt1, Wut, bm, Xc, Zc, Uc);

  // ---- layer 0: table-gather edge + rank-decomposed update GEMM ----
  edge0_kernel<<<NN_ / 4, 256, 0, stream>>>(Xc, Zc, posA, rowptr, src_s,
                                            Wm + 512 * H_, Wp, aggb, posB);
  upd2_dec<<<NN_ / 64, 256, 0, stream>>>(hbf, aggb, Wut + 65536, Uc, bu);

  // ---- layer 1: full path (bf16 X table; pos update dead in final layer) ----
  gemm1_mfma<<<NN_ / 64, 256, 0, stream>>>(hbf, Wt1 + 131072,
                                           bm + H_, X, Zb);
  edge_kernel<<<NN_ / 4, 256, 0, stream>>>(X, Zb, posB, rowptr, src_s,
                                           Wm + (size_t)513 * H_ + 512 * H_,
                                           aggb);
  upd2_out<<<NN_ / 64, 256, 0, stream>>>(hbf, aggb, Wut + 131072,
                                         bu + H_, W_out, b_out, out);
}

// Round 14
// 294.216 us; speedup vs baseline: 1.0298x; 1.0148x over previous
//
#include <hip/hip_runtime.h>
#include <math.h>

#define B_ 32
#define F_ 128
#define H_ 256
#define N_ 2048
#define L_ 2
#define E_ 262144
#define NN_ 65536          // B_*N_
// DEG = E/(B*N) = 4

typedef __attribute__((ext_vector_type(8))) short short8;   // 8 bf16 = 4 VGPRs (MFMA A/B frag)
typedef __attribute__((ext_vector_type(4))) float f32x4;    // MFMA C/D frag
typedef __attribute__((ext_vector_type(2))) float f32x2;    // packed-FP32 pair (v_pk_*_f32)

static __device__ __forceinline__ unsigned short f2bf(float f) {
  unsigned int u = __float_as_uint(f);
  u += 0x7FFF + ((u >> 16) & 1);      // round-to-nearest-even
  return (unsigned short)(u >> 16);
}
static __device__ __forceinline__ float bf2f(unsigned short u) {
  return __uint_as_float(((unsigned int)u) << 16);
}
// 2×f32 -> packed 2×bf16 in one u32 (RNE), single instruction
static __device__ __forceinline__ unsigned int pk_bf16(float lo, float hi) {
  unsigned int r;
  asm("v_cvt_pk_bf16_f32 %0, %1, %2" : "=v"(r) : "v"(lo), "v"(hi));
  return r;
}

// async global->LDS, 16B per lane; LDS dest = wave-uniform base + lane*16
typedef const __attribute__((address_space(1))) unsigned int* as1p;
typedef __attribute__((address_space(3))) unsigned int* as3p;
static __device__ __forceinline__ void gload16(const void* g, void* l) {
  __builtin_amdgcn_global_load_lds((as1p)g, (as3p)l, 16, 0, 0);
}

// ---------------- mega1: deg | wconv | h0 | meand_g (all independent) ----------------
// blocks: [0,1024) deg ; [1024,1280) wconv ; [1280,1312) h0 ; [1312,3360) meand_g
__global__ void mega1_kernel(const int* __restrict__ ei, int* __restrict__ deg,
                             const float* __restrict__ Wm, const float* __restrict__ Wu,
                             unsigned short* __restrict__ Wt1, unsigned short* __restrict__ Wut,
                             const float* __restrict__ x, const float* __restrict__ W_in,
                             const float* __restrict__ b_in, float* __restrict__ h0,
                             const float* __restrict__ positions,
                             const float* __restrict__ Wg1, const float* __restrict__ bg1,
                             const float* __restrict__ Wg2, const float* __restrict__ bg2,
                             float* __restrict__ g) {
  __shared__ float red[256];
  __shared__ float hid[128];
  const int blk = blockIdx.x;
  const int t = threadIdx.x;
  if (blk < 1024) {
    // deg
    int e = blk * 256 + t;
    atomicAdd(&deg[ei[E_ + e]], 1);
  } else if (blk < 1280) {
    // wconv (frag-order weight conversion)
    int idx = (blk - 1024) * 256 + t;            // 0..65535
    int sel = idx >> 14;                          // 0,1: Wm l0,l1 ; 2,3: Wu l0,l1
    int rem = idx & 16383;
    if (sel < 2) {
      const float* W = Wm + (size_t)sel * 513 * H_;
      unsigned short* dst = Wt1 + (size_t)sel * 131072 + ((size_t)rem << 3);
      int gg = rem >> 13;
      int r2 = rem & 8191;
      int kc = r2 >> 11, w = (r2 >> 9) & 3, ks = (r2 >> 8) & 1, ni = (r2 >> 6) & 3, lane = r2 & 63;
      int r = lane & 15, q = lane >> 4;
      int n  = (w << 6) + (ni << 4) + r;
      int kb = (gg << 8) + (kc << 6) + (ks << 5) + (q << 3);
#pragma unroll
      for (int j = 0; j < 8; ++j)
        dst[j] = f2bf(W[(size_t)(kb + j) * H_ + n]);
    } else {
      const float* W = Wu + (size_t)(sel - 2) * 512 * H_;
      unsigned short* dst = Wut + (size_t)(sel - 2) * 131072 + ((size_t)rem << 3);
      int kc = rem >> 11, w = (rem >> 9) & 3, ks = (rem >> 8) & 1, ni = (rem >> 6) & 3, lane = rem & 63;
      int r = lane & 15, q = lane >> 4;
      int n  = (w << 6) + (ni << 4) + r;
      int kb = (kc << 6) + (ks << 5) + (q << 3);
#pragma unroll
      for (int j = 0; j < 8; ++j)
        dst[j] = f2bf(W[(size_t)(kb + j) * H_ + n]);
    }
  } else if (blk < 1312) {
    // h0
    int b = blk - 1280;
    float acc = b_in[t];
#pragma unroll 8
    for (int k = 0; k < F_; ++k)
      acc += x[b * F_ + k] * W_in[k * H_ + t];
    h0[b * H_ + t] = acc;
  } else {
    // meand_g: one block per node n
    int n = blk - 1312;
    float px = positions[n * 3 + 0], py = positions[n * 3 + 1], pz = positions[n * 3 + 2];
    float s = 0.f;
    for (int j = t; j < N_; j += 256) {
      float dx = px - positions[j * 3 + 0];
      float dy = py - positions[j * 3 + 1];
      float dz = pz - positions[j * 3 + 2];
      s += sqrtf(dx * dx + dy * dy + dz * dz);
    }
    red[t] = s;
    __syncthreads();
    for (int off = 128; off > 0; off >>= 1) {
      if (t < off) red[t] += red[t + off];
      __syncthreads();
    }
    float md = red[0] / (float)(N_ - 1);
    if (t < 128) {
      float w = Wg1[t] + Wg1[128 + t] + Wg1[256 + t];
      hid[t] = fmaxf(md * w + bg1[t], 0.f);
    }
    __syncthreads();
    float acc = bg2[t];
#pragma unroll 8
    for (int k = 0; k < 128; ++k)
      acc += hid[k] * Wg2[k * H_ + t];
    g[n * H_ + t] = acc;
  }
}

// ---------------- CSR scans (unchanged, small) ----------------

__global__ void scan1_kernel(const int* __restrict__ deg, int* __restrict__ bsum) {
  __shared__ int red[256];
  int t = threadIdx.x;
  red[t] = deg[blockIdx.x * 256 + t];
  __syncthreads();
  for (int off = 128; off > 0; off >>= 1) {
    if (t < off) red[t] += red[t + off];
    __syncthreads();
  }
  if (t == 0) bsum[blockIdx.x] = red[0];
}

__global__ void scan2_kernel(int* __restrict__ bsum) {
  __shared__ int s[256];
  int t = threadIdx.x;
  s[t] = bsum[t];
  __syncthreads();
  for (int off = 1; off < 256; off <<= 1) {
    int v = (t >= off) ? s[t - off] : 0;
    __syncthreads();
    s[t] += v;
    __syncthreads();
  }
  bsum[t] = (t == 0) ? 0 : s[t - 1];
}

// ---------------- mega2: scan3 | initpack ----------------
// blocks [0,256): scan3 ; [256, 8964): initpack
__global__ void mega2_kernel(const int* __restrict__ deg, const int* __restrict__ bsum,
                             int* __restrict__ cur, int* __restrict__ rowptr,
                             const float* __restrict__ h0, const float* __restrict__ g,
                             const float* __restrict__ positions,
                             unsigned short* __restrict__ hbf,
                             unsigned short* __restrict__ hg,
                             float* __restrict__ pos4) {
  __shared__ int s[256];
  const int blk0 = blockIdx.x;
  const int t = threadIdx.x;
  if (blk0 < 256) {
    // scan3: writes BOTH cur and rowptr
    int i = blk0 * 256 + t;
    s[t] = deg[i];
    __syncthreads();
    for (int off = 1; off < 256; off <<= 1) {
      int v = (t >= off) ? s[t - off] : 0;
      __syncthreads();
      s[t] += v;
      __syncthreads();
    }
    int excl = (t == 0) ? 0 : s[t - 1];
    int v = bsum[blk0] + excl;
    cur[i] = v;
    rowptr[i] = v;
    return;
  }
  const int blk = blk0 - 256;
  if (blk < 8192) {
    int idx = blk * 256 + t;  // NN*32, 8 ch each
    int row = idx >> 5;
    int c8 = (idx & 31) << 3;
    const float* hp = h0 + (row >> 11) * H_ + c8;
    const float* gp = g + (row & (N_ - 1)) * H_ + c8;
    const float4 a = *(const float4*)hp;
    const float4 a2 = *(const float4*)(hp + 4);
    const float4 b = *(const float4*)gp;
    const float4 b2 = *(const float4*)(gp + 4);
    short8 v;
    v[0] = (short)f2bf(a.x + b.x);  v[1] = (short)f2bf(a.y + b.y);
    v[2] = (short)f2bf(a.z + b.z);  v[3] = (short)f2bf(a.w + b.w);
    v[4] = (short)f2bf(a2.x + b2.x); v[5] = (short)f2bf(a2.y + b2.y);
    v[6] = (short)f2bf(a2.z + b2.z); v[7] = (short)f2bf(a2.w + b2.w);
    *(short8*)(hbf + (((size_t)row) << 8) + c8) = v;
  } else if (blk < 8452) {
    int idx = (blk - 8192) * 256 + t;  // 2080*32, 8 ch each
    int row = idx >> 5;
    int c8 = (idx & 31) << 3;
    const float* src = (row < 2048) ? (g + (size_t)row * H_ + c8)
                                    : (h0 + (size_t)(row - 2048) * H_ + c8);
    const float4 a = *(const float4*)src;
    const float4 a2 = *(const float4*)(src + 4);
    short8 v;
    v[0] = (short)f2bf(a.x);  v[1] = (short)f2bf(a.y);
    v[2] = (short)f2bf(a.z);  v[3] = (short)f2bf(a.w);
    v[4] = (short)f2bf(a2.x); v[5] = (short)f2bf(a2.y);
    v[6] = (short)f2bf(a2.z); v[7] = (short)f2bf(a2.w);
    *(short8*)(hg + (((size_t)row) << 8) + c8) = v;
  } else {
    int n = (blk - 8452) * 256 + t;   // 0..NN-1
    int src = (n & (N_ - 1)) * 3;
    float4 v;
    v.x = positions[src + 0];
    v.y = positions[src + 1];
    v.z = positions[src + 2];
    v.w = 0.f;
    *(float4*)(pos4 + ((size_t)n << 2)) = v;
  }
}

// ============ counted-vmcnt pipelined GEMM (K=32 phases, 4 buffers, depth-3) ============
// (round-5 proven structure)

#define GEMM_IDS(BID)                                                \
  const int t = threadIdx.x;                                         \
  const int m0 = (BID) << 6;                                         \
  const int wu = __builtin_amdgcn_readfirstlane(t >> 6);             \
  const int lane = t & 63;                                           \
  const int q = lane >> 4;                                           \
  const int r = lane & 15;                                           \
  const int arow = lane >> 2;                                        \
  const int aq = (lane & 3) ^ ((lane >> 2) & 3);   /* pre-swizzled src quad */

#define STAGE_P(P, abase)                                                                \
  do {                                                                                   \
    gload16((abase) + (((size_t)(m0 + (wu << 4) + arow)) << 8) + (((P) & 7) << 5) +      \
                (aq << 3),                                                               \
            &sA[(P) & 3][wu << 9]);                                                      \
    _Pragma("unroll")                                                                    \
    for (int j_ = 0; j_ < 4; ++j_)                                                       \
      gload16(Wt + (((size_t)((P) >> 1)) << 14) + (wu << 12) + (((P) & 1) << 11) +       \
                  (j_ << 9) + (lane << 3),                                               \
              &sB[(P) & 3][(wu << 11) + (j_ << 9)]);                                     \
  } while (0)

#define COMPUTE_P(P)                                                                     \
  do {                                                                                   \
    short8 af[4], bfr[4];                                                                \
    _Pragma("unroll")                                                                    \
    for (int mi = 0; mi < 4; ++mi)                                                       \
      af[mi] = *(const short8*)(&sA[(P) & 3][((mi * 16 + r) << 5) +                      \
                                             ((q ^ (r & 3)) << 3)]);                     \
    _Pragma("unroll")                                                                    \
    for (int ni = 0; ni < 4; ++ni)                                                       \
      bfr[ni] = *(const short8*)(&sB[(P) & 3][(wu << 11) + (ni << 9) + (lane << 3)]);    \
    _Pragma("unroll")                                                                    \
    for (int mi = 0; mi < 4; ++mi)                                                       \
      _Pragma("unroll")                                                                  \
      for (int ni = 0; ni < 4; ++ni)                                                     \
        acc[mi][ni] = __builtin_amdgcn_mfma_f32_16x16x32_bf16(af[mi], bfr[ni],           \
                                                              acc[mi][ni], 0, 0, 0);     \
  } while (0)

// 16-phase wait schedule
#define WAIT_BAR(P)                                                       \
  do {                                                                    \
    if ((P) <= 13)      asm volatile("s_waitcnt vmcnt(10)" ::: "memory"); \
    else if ((P) == 14) asm volatile("s_waitcnt vmcnt(5)" ::: "memory");  \
    else                asm volatile("s_waitcnt vmcnt(0)" ::: "memory");  \
    __builtin_amdgcn_s_barrier();                                         \
    asm volatile("" ::: "memory");                                        \
  } while (0)

// 8-phase wait schedule
#define WAIT_BAR8(P)                                                      \
  do {                                                                    \
    if ((P) <= 5)       asm volatile("s_waitcnt vmcnt(10)" ::: "memory"); \
    else if ((P) == 6)  asm volatile("s_waitcnt vmcnt(5)" ::: "memory");  \
    else                asm volatile("s_waitcnt vmcnt(0)" ::: "memory");  \
    __builtin_amdgcn_s_barrier();                                         \
    asm volatile("" ::: "memory");                                        \
  } while (0)

#define ACC_ZERO()                                   \
  _Pragma("unroll")                                  \
  for (int mi = 0; mi < 4; ++mi)                     \
    _Pragma("unroll")                                \
    for (int ni = 0; ni < 4; ++ni)                   \
      acc[mi][ni] = (f32x4){0.f, 0.f, 0.f, 0.f};

// ---------------- mega3: scatter | gemm1_small | Uc-small-GEMM ----------------
// blocks [0,1024): scatter ; [1024,1057): gemm1_small (Wm l0, 16 phases)
// [1057,1090): Uc GEMM  (hg @ Wu_l0[0:256,:] -> Uc, 8 phases)
__launch_bounds__(256)
__global__ void mega3_kernel(const int* __restrict__ ei, int* __restrict__ cur,
                             int* __restrict__ src_s,
                             const unsigned short* __restrict__ hg,
                             const unsigned short* __restrict__ Wtm,   // Wm layer0 frag
                             const unsigned short* __restrict__ Wtu,   // Wu layer0 frag
                             const float* __restrict__ bm,
                             float* __restrict__ Xc, float* __restrict__ Zc,
                             float* __restrict__ Uc) {
  __shared__ __align__(16) unsigned short sA[4][2048];
  __shared__ __align__(16) unsigned short sB[4][8192];
  const int blk = blockIdx.x;
  if (blk < 1024) {
    // scatter
    int e = blk * 256 + threadIdx.x;
    int s = ei[e], d = ei[E_ + e];
    int p = atomicAdd(&cur[d], 1);
    src_s[p] = s;
    return;
  }
  if (blk < 1057) {
    // gemm1_small: layer-0 rank decomposition (2112 rows, f32 out), K=512 of Wm
    const int bid = blk - 1024;
    const unsigned short* Wt = Wtm;
    GEMM_IDS(bid)

    f32x4 acc[4][4];
    ACC_ZERO();

    STAGE_P(0, hg); STAGE_P(1, hg); STAGE_P(2, hg);
#pragma unroll
    for (int p = 0; p < 16; ++p) {
      WAIT_BAR(p);
      if (p + 3 < 16) STAGE_P(p + 3, hg);
      COMPUTE_P(p);
      if (p == 7) {
#pragma unroll
        for (int ni = 0; ni < 4; ++ni) {
          int n = (wu << 6) + ni * 16 + r;
#pragma unroll
          for (int mi = 0; mi < 4; ++mi)
#pragma unroll
            for (int reg = 0; reg < 4; ++reg) {
              size_t idx = (((size_t)(m0 + mi * 16 + q * 4 + reg)) << 8) + n;
              Xc[idx] = acc[mi][ni][reg];
              acc[mi][ni][reg] = 0.f;
            }
        }
      }
    }

    const int isH0 = (bid == 32);   // rows 2048.. carry h0 -> bias lives here
#pragma unroll
    for (int ni = 0; ni < 4; ++ni) {
      int n = (wu << 6) + ni * 16 + r;
      float bmn = isH0 ? bm[n] : 0.f;
#pragma unroll
      for (int mi = 0; mi < 4; ++mi)
#pragma unroll
        for (int reg = 0; reg < 4; ++reg) {
          size_t idx = (((size_t)(m0 + mi * 16 + q * 4 + reg)) << 8) + n;
          Zc[idx] = acc[mi][ni][reg] + bmn;
        }
    }
    return;
  }
  // Uc GEMM: hg @ Wu_l0 rows 0..255 (pieces 0..3), 8 phases, f32 out (no bias)
  {
    const int bid = blk - 1057;
    const unsigned short* Wt = Wtu;
    GEMM_IDS(bid)

    f32x4 acc[4][4];
    ACC_ZERO();

    STAGE_P(0, hg); STAGE_P(1, hg); STAGE_P(2, hg);
#pragma unroll
    for (int p = 0; p < 8; ++p) {
      WAIT_BAR8(p);
      if (p + 3 < 8) STAGE_P(p + 3, hg);
      COMPUTE_P(p);
    }
#pragma unroll
    for (int ni = 0; ni < 4; ++ni) {
      int n = (wu << 6) + ni * 16 + r;
#pragma unroll
      for (int mi = 0; mi < 4; ++mi)
#pragma unroll
        for (int reg = 0; reg < 4; ++reg) {
          size_t idx = (((size_t)(m0 + mi * 16 + q * 4 + reg)) << 8) + n;
          Uc[idx] = acc[mi][ni][reg];
        }
    }
  }
}

// ---------------- GEMM1: 16 phases (p0-7: g=0 -> X bf16, p8-15: g=1 -> Zb bf16) ----------------
__launch_bounds__(256)
__global__ void gemm1_mfma(const unsigned short* __restrict__ hbf,
                           const unsigned short* __restrict__ Wt,
                           const float* __restrict__ bm,
                           unsigned short* __restrict__ X, unsigned short* __restrict__ Zb) {
  __shared__ __align__(16) unsigned short sA[4][2048];
  __shared__ __align__(16) unsigned short sB[4][8192];
  GEMM_IDS(blockIdx.x)

  f32x4 acc[4][4];
  ACC_ZERO();

  STAGE_P(0, hbf); STAGE_P(1, hbf); STAGE_P(2, hbf);
#pragma unroll
  for (int p = 0; p < 16; ++p) {
    WAIT_BAR(p);
    if (p + 3 < 16) STAGE_P(p + 3, hbf);
    COMPUTE_P(p);
    if (p == 7) {
      // g=0 half done: store X, reset acc
#pragma unroll
      for (int ni = 0; ni < 4; ++ni) {
        int n = (wu << 6) + ni * 16 + r;
#pragma unroll
        for (int mi = 0; mi < 4; ++mi)
#pragma unroll
          for (int reg = 0; reg < 4; ++reg) {
            size_t idx = (((size_t)(m0 + mi * 16 + q * 4 + reg)) << 8) + n;
            X[idx] = f2bf(acc[mi][ni][reg]);
            acc[mi][ni][reg] = 0.f;
          }
      }
    }
  }

  // g=1 half: store Zb (+bm)
#pragma unroll
  for (int ni = 0; ni < 4; ++ni) {
    int n = (wu << 6) + ni * 16 + r;
    float bmn = bm[n];
#pragma unroll
    for (int mi = 0; mi < 4; ++mi)
#pragma unroll
      for (int reg = 0; reg < 4; ++reg) {
        size_t idx = (((size_t)(m0 + mi * 16 + q * 4 + reg)) << 8) + n;
        Zb[idx] = f2bf(acc[mi][ni][reg] + bmn);
      }
  }
}

// ---------------- edge kernels: round-11 proven (1 node/wave, scalar CSR, 4-wide groups) ----------------
static __device__ __forceinline__ void edge_core(
    const float4 pn, const float4 q,
    f32x2 x01, f32x2 x23,
    const f32x2 z01, const f32x2 z23,
    const f32x2 wl01, const f32x2 wl23,
    const f32x2 wp01, const f32x2 wp23,
    f32x2& a01, f32x2& a23,
    float& pdx, float& pdy, float& pdz) {
  const float dx = pn.x - q.x, dy = pn.y - q.y, dz = pn.z - q.z;
  const float d = sqrtf(dx * dx + dy * dy + dz * dz + 1e-12f);
  f32x2 dd; dd[0] = d; dd[1] = d;
  f32x2 v01 = x01 + z01 + dd * wl01;          // v_pk_add + v_pk_fma
  f32x2 v23 = x23 + z23 + dd * wl23;
  v01[0] = fmaxf(v01[0], 0.f); v01[1] = fmaxf(v01[1], 0.f);
  v23[0] = fmaxf(v23[0], 0.f); v23[1] = fmaxf(v23[1], 0.f);
  a01 += v01; a23 += v23;
  const f32x2 cpv = v01 * wp01 + v23 * wp23;  // v_pk_mul + v_pk_fma
  const float cp = cpv[0] + cpv[1];
  pdx += dx * cp; pdy += dy * cp; pdz += dz * cp;
}

// no-pos variant: final-layer position update is dead code in the reference
static __device__ __forceinline__ void edge_core_np(
    const float4 pn, const float4 q,
    f32x2 x01, f32x2 x23,
    const f32x2 z01, const f32x2 z23,
    const f32x2 wl01, const f32x2 wl23,
    f32x2& a01, f32x2& a23) {
  const float dx = pn.x - q.x, dy = pn.y - q.y, dz = pn.z - q.z;
  const float d = sqrtf(dx * dx + dy * dy + dz * dz + 1e-12f);
  f32x2 dd; dd[0] = d; dd[1] = d;
  f32x2 v01 = x01 + z01 + dd * wl01;
  f32x2 v23 = x23 + z23 + dd * wl23;
  v01[0] = fmaxf(v01[0], 0.f); v01[1] = fmaxf(v01[1], 0.f);
  v23[0] = fmaxf(v23[0], 0.f); v23[1] = fmaxf(v23[1], 0.f);
  a01 += v01; a23 += v23;
}

static __device__ __forceinline__ void edge_do_np(
    const float4 pn, const float4 q, const uint2 xv,
    const f32x2 z01, const f32x2 z23,
    const f32x2 wl01, const f32x2 wl23,
    f32x2& a01, f32x2& a23) {
  f32x2 x01, x23;
  x01[0] = __uint_as_float(xv.x << 16);
  x01[1] = __uint_as_float(xv.x & 0xffff0000u);
  x23[0] = __uint_as_float(xv.y << 16);
  x23[1] = __uint_as_float(xv.y & 0xffff0000u);
  edge_core_np(pn, q, x01, x23, z01, z23, wl01, wl23, a01, a23);
}

static __device__ __forceinline__ void edge_do0(
    const float4 pn, const float4 q, const float4 xg, const float4 xh,
    const f32x2 z01, const f32x2 z23,
    const f32x2 wl01, const f32x2 wl23,
    const f32x2 wp01, const f32x2 wp23,
    f32x2& a01, f32x2& a23,
    float& pdx, float& pdy, float& pdz) {
  f32x2 x01, x23;
  x01[0] = xg.x + xh.x; x01[1] = xg.y + xh.y;
  x23[0] = xg.z + xh.z; x23[1] = xg.w + xh.w;
  edge_core(pn, q, x01, x23, z01, z23, wl01, wl23, wp01, wp23, a01, a23, pdx, pdy, pdz);
}

// layer-1 edge (FINAL layer): pos/coef path removed — dead in reference.
__launch_bounds__(256)
__global__ void edge_kernel(const unsigned short* __restrict__ X,
                            const unsigned short* __restrict__ Zb,
                            const float* __restrict__ pos_c,   // stride-4
                            const int* __restrict__ rowptr, const int* __restrict__ src_s,
                            const float* __restrict__ wl,
                            unsigned short* __restrict__ aggb) {
  const int gid = blockIdx.x * 256 + threadIdx.x;
  // n is wave-uniform; force SGPR so the CSR walk is scalar.
  const int n = __builtin_amdgcn_readfirstlane(gid >> 6);
  const int lane = threadIdx.x & 63;

  const float4 wlv = *(const float4*)(wl + (lane << 2));
  const f32x2 wl01 = {wlv.x, wlv.y}, wl23 = {wlv.z, wlv.w};

  const int e0 = rowptr[n];
  const int e1 = (n == NN_ - 1) ? E_ : rowptr[n + 1];

  const uint2 zv = *(const uint2*)(Zb + (((size_t)n) << 8) + (lane << 2));
  f32x2 z01, z23;
  z01[0] = __uint_as_float(zv.x << 16);
  z01[1] = __uint_as_float(zv.x & 0xffff0000u);
  z23[0] = __uint_as_float(zv.y << 16);
  z23[1] = __uint_as_float(zv.y & 0xffff0000u);

  const float4 pn = *(const float4*)(pos_c + ((size_t)n << 2));
  f32x2 a01 = {0.f, 0.f}, a23 = {0.f, 0.f};

  const unsigned short* Xl = X + (lane << 2);

  int e = e0;
  for (; e + 4 <= e1; e += 4) {
    const int s0 = src_s[e], s1 = src_s[e + 1], s2 = src_s[e + 2], s3 = src_s[e + 3];
    const float4 q0 = *(const float4*)(pos_c + ((size_t)s0 << 2));
    const float4 q1 = *(const float4*)(pos_c + ((size_t)s1 << 2));
    const float4 q2 = *(const float4*)(pos_c + ((size_t)s2 << 2));
    const float4 q3 = *(const float4*)(pos_c + ((size_t)s3 << 2));
    const uint2 x0 = *(const uint2*)(Xl + (((size_t)s0) << 8));
    const uint2 x1 = *(const uint2*)(Xl + (((size_t)s1) << 8));
    const uint2 x2 = *(const uint2*)(Xl + (((size_t)s2) << 8));
    const uint2 x3 = *(const uint2*)(Xl + (((size_t)s3) << 8));
    edge_do_np(pn, q0, x0, z01, z23, wl01, wl23, a01, a23);
    edge_do_np(pn, q1, x1, z01, z23, wl01, wl23, a01, a23);
    edge_do_np(pn, q2, x2, z01, z23, wl01, wl23, a01, a23);
    edge_do_np(pn, q3, x3, z01, z23, wl01, wl23, a01, a23);
  }
  if (e + 2 <= e1) {
    const int s0 = src_s[e], s1 = src_s[e + 1];
    const float4 q0 = *(const float4*)(pos_c + ((size_t)s0 << 2));
    const float4 q1 = *(const float4*)(pos_c + ((size_t)s1 << 2));
    const uint2 x0 = *(const uint2*)(Xl + (((size_t)s0) << 8));
    const uint2 x1 = *(const uint2*)(Xl + (((size_t)s1) << 8));
    edge_do_np(pn, q0, x0, z01, z23, wl01, wl23, a01, a23);
    edge_do_np(pn, q1, x1, z01, z23, wl01, wl23, a01, a23);
    e += 2;
  }
  if (e < e1) {
    const int s0 = src_s[e];
    const float4 q0 = *(const float4*)(pos_c + ((size_t)s0 << 2));
    const uint2 x0 = *(const uint2*)(Xl + (((size_t)s0) << 8));
    edge_do_np(pn, q0, x0, z01, z23, wl01, wl23, a01, a23);
  }

  uint2 av;
  av.x = pk_bf16(a01[0], a01[1]);
  av.y = pk_bf16(a23[0], a23[1]);
  *(uint2*)(aggb + (((size_t)n) << 8) + (lane << 2)) = av;
}

// layer-0 edge: X/Z from rank-decomposed f32 tables Xc/Zc (2112 rows; L2-hot).
// Layer-0 positions are batch-replicated: posA[n] = positions[n & 2047], so all
// pos gathers are masked into rows 0..2047 (32 KB, L1-resident) — same values.
__launch_bounds__(256)
__global__ void edge0_kernel(const float* __restrict__ Xc,
                             const float* __restrict__ Zc,
                             const float* __restrict__ pos_c,   // stride-4
                             const int* __restrict__ rowptr, const int* __restrict__ src_s,
                             const float* __restrict__ wl, const float* __restrict__ wp,
                             unsigned short* __restrict__ aggb, float* __restrict__ pos_o) {
  const int gid = blockIdx.x * 256 + threadIdx.x;
  const int n = __builtin_amdgcn_readfirstlane(gid >> 6);
  const int lane = threadIdx.x & 63;

  const float4 wlv = *(const float4*)(wl + (lane << 2));
  const float4 wpv = *(const float4*)(wp + (lane << 2));
  const f32x2 wl01 = {wlv.x, wlv.y}, wl23 = {wlv.z, wlv.w};
  const f32x2 wp01 = {wpv.x, wpv.y}, wp23 = {wpv.z, wpv.w};

  const int e0 = rowptr[n];
  const int e1 = (n == NN_ - 1) ? E_ : rowptr[n + 1];

  const float* Xl = Xc + (lane << 2);
  const float* Zl = Zc + (lane << 2);

  // z = Zg[node] + Zh0[batch] (Zh0 carries bm)
  const float4 zg = *(const float4*)(Zl + (((size_t)(n & (N_ - 1))) << 8));
  const float4 zh = *(const float4*)(Zl + (((size_t)(2048 + (n >> 11))) << 8));
  f32x2 z01, z23;
  z01[0] = zg.x + zh.x; z01[1] = zg.y + zh.y;
  z23[0] = zg.z + zh.z; z23[1] = zg.w + zh.w;

  const float4 pn = *(const float4*)(pos_c + ((size_t)(n & (N_ - 1)) << 2));
  f32x2 a01 = {0.f, 0.f}, a23 = {0.f, 0.f};
  float pdx = 0.f, pdy = 0.f, pdz = 0.f;

  int e = e0;
  for (; e + 4 <= e1; e += 4) {
    const int s0 = src_s[e], s1 = src_s[e + 1], s2 = src_s[e + 2], s3 = src_s[e + 3];
    const float4 q0 = *(const float4*)(pos_c + ((size_t)(s0 & (N_ - 1)) << 2));
    const float4 q1 = *(const float4*)(pos_c + ((size_t)(s1 & (N_ - 1)) << 2));
    const float4 q2 = *(const float4*)(pos_c + ((size_t)(s2 & (N_ - 1)) << 2));
    const float4 q3 = *(const float4*)(pos_c + ((size_t)(s3 & (N_ - 1)) << 2));
    const float4 xg0 = *(const float4*)(Xl + (((size_t)(s0 & (N_ - 1))) << 8));
    const float4 xh0 = *(const float4*)(Xl + (((size_t)(2048 + (s0 >> 11))) << 8));
    const float4 xg1 = *(const float4*)(Xl + (((size_t)(s1 & (N_ - 1))) << 8));
    const float4 xh1 = *(const float4*)(Xl + (((size_t)(2048 + (s1 >> 11))) << 8));
    const float4 xg2 = *(const float4*)(Xl + (((size_t)(s2 & (N_ - 1))) << 8));
    const float4 xh2 = *(const float4*)(Xl + (((size_t)(2048 + (s2 >> 11))) << 8));
    const float4 xg3 = *(const float4*)(Xl + (((size_t)(s3 & (N_ - 1))) << 8));
    const float4 xh3 = *(const float4*)(Xl + (((size_t)(2048 + (s3 >> 11))) << 8));
    edge_do0(pn, q0, xg0, xh0, z01, z23, wl01, wl23, wp01, wp23, a01, a23, pdx, pdy, pdz);
    edge_do0(pn, q1, xg1, xh1, z01, z23, wl01, wl23, wp01, wp23, a01, a23, pdx, pdy, pdz);
    edge_do0(pn, q2, xg2, xh2, z01, z23, wl01, wl23, wp01, wp23, a01, a23, pdx, pdy, pdz);
    edge_do0(pn, q3, xg3, xh3, z01, z23, wl01, wl23, wp01, wp23, a01, a23, pdx, pdy, pdz);
  }
  for (; e < e1; ++e) {
    const int s0 = src_s[e];
    const float4 q0 = *(const float4*)(pos_c + ((size_t)(s0 & (N_ - 1)) << 2));
    const float4 xg0 = *(const float4*)(Xl + (((size_t)(s0 & (N_ - 1))) << 8));
    const float4 xh0 = *(const float4*)(Xl + (((size_t)(2048 + (s0 >> 11))) << 8));
    edge_do0(pn, q0, xg0, xh0, z01, z23, wl01, wl23, wp01, wp23, a01, a23, pdx, pdy, pdz);
  }

  uint2 av;
  av.x = pk_bf16(a01[0], a01[1]);
  av.y = pk_bf16(a23[0], a23[1]);
  *(uint2*)(aggb + (((size_t)n) << 8) + (lane << 2)) = av;

#pragma unroll
  for (int m = 1; m < 64; m <<= 1) {
    pdx += __shfl_xor(pdx, m, 64);
    pdy += __shfl_xor(pdy, m, 64);
    pdz += __shfl_xor(pdz, m, 64);
  }
  if (lane == 0) {
    float4 po;
    po.x = pn.x + pdx * 0.25f;
    po.y = pn.y + pdy * 0.25f;
    po.z = pn.z + pdz * 0.25f;
    po.w = 0.f;
    *(float4*)(pos_o + ((size_t)n << 2)) = po;
  }
}

// ---------------- GEMM2 layer-0: rank-decomposed hbf half (acc init from Uc) ----------------
// acc = Uc[g-part] + Uc[h0-part]  (K=0..255 contribution), then 8 phases over aggb (K=256..511).
// Wt must point at Wu-layer0 frag pieces 4..7 (i.e. Wut + 65536).
__launch_bounds__(256)
__global__ void upd2_dec(unsigned short* __restrict__ hbf,
                         const unsigned short* __restrict__ aggb,
                         const unsigned short* __restrict__ Wt,
                         const float* __restrict__ Uc,
                         const float* __restrict__ bu) {
  __shared__ __align__(16) unsigned short sA[4][2048];
  __shared__ __align__(16) unsigned short sB[4][8192];
  GEMM_IDS(blockIdx.x)

  const int nn0 = m0 & (N_ - 1);   // block's 64 rows share one batch (64 | 2048)
  const int bb  = m0 >> 11;

  f32x4 acc[4][4];
  // acc init from Uc: 64 consecutive g-rows + one block-uniform h0 row.
#pragma unroll
  for (int ni = 0; ni < 4; ++ni) {
    int n = (wu << 6) + ni * 16 + r;
    float uh = Uc[(((size_t)(2048 + bb)) << 8) + n];
#pragma unroll
    for (int mi = 0; mi < 4; ++mi)
#pragma unroll
      for (int reg = 0; reg < 4; ++reg) {
        int rl = mi * 16 + q * 4 + reg;
        acc[mi][ni][reg] = Uc[(((size_t)(nn0 + rl)) << 8) + n] + uh;
      }
  }

  STAGE_P(0, aggb); STAGE_P(1, aggb); STAGE_P(2, aggb);
#pragma unroll
  for (int p = 0; p < 8; ++p) {
    WAIT_BAR8(p);
    if (p + 3 < 8) STAGE_P(p + 3, aggb);
    COMPUTE_P(p);
  }

  // epilogue: residual add; hbf rows are L2-hot
#pragma unroll
  for (int ni = 0; ni < 4; ++ni) {
    int n = (wu << 6) + ni * 16 + r;
    float buv = bu[n];
#pragma unroll
    for (int mi = 0; mi < 4; ++mi)
#pragma unroll
      for (int reg = 0; reg < 4; ++reg) {
        size_t idx = (((size_t)(m0 + mi * 16 + q * 4 + reg)) << 8) + n;
        float v = bf2f(hbf[idx]) + fmaxf(acc[mi][ni][reg] + buv, 0.f);
        hbf[idx] = f2bf(v);
      }
  }
}

// ---------------- GEMM2 final layer with fused W_out projection ----------------
__launch_bounds__(256)
__global__ void upd2_out(const unsigned short* __restrict__ hbf,
                         const unsigned short* __restrict__ aggb,
                         const unsigned short* __restrict__ Wt,
                         const float* __restrict__ bu,
                         const float* __restrict__ Wout, const float* __restrict__ bout,
                         float* __restrict__ out) {
  __shared__ __align__(16) unsigned short sA[4][2048];
  __shared__ __align__(16) unsigned short sB[4][8192];
  GEMM_IDS(blockIdx.x)

  f32x4 acc[4][4];
  ACC_ZERO();

  STAGE_P(0, hbf); STAGE_P(1, hbf); STAGE_P(2, hbf);
#pragma unroll
  for (int p = 0; p < 16; ++p) {
    WAIT_BAR(p);
    if (p + 3 < 16) {
      const unsigned short* ab = (p + 3 < 8) ? hbf : aggb;
      STAGE_P(p + 3, ab);
    }
    COMPUTE_P(p);
  }
  __syncthreads();                      // LDS reads done; safe to reuse sA for sRed
  float (*sRed)[64] = (float(*)[64])(&sA[0][0]);

  float dotp[4][4];
#pragma unroll
  for (int mi = 0; mi < 4; ++mi)
#pragma unroll
    for (int reg = 0; reg < 4; ++reg)
      dotp[mi][reg] = 0.f;

#pragma unroll
  for (int ni = 0; ni < 4; ++ni) {
    int n = (wu << 6) + ni * 16 + r;
    float buv = bu[n];
    float won = Wout[n];
#pragma unroll
    for (int mi = 0; mi < 4; ++mi)
#pragma unroll
      for (int reg = 0; reg < 4; ++reg) {
        size_t idx = (((size_t)(m0 + mi * 16 + q * 4 + reg)) << 8) + n;
        float v = bf2f(hbf[idx]) + fmaxf(acc[mi][ni][reg] + buv, 0.f);
        dotp[mi][reg] += v * won;
      }
  }
#pragma unroll
  for (int mask = 1; mask < 16; mask <<= 1)
#pragma unroll
    for (int mi = 0; mi < 4; ++mi)
#pragma unroll
      for (int reg = 0; reg < 4; ++reg)
        dotp[mi][reg] += __shfl_xor(dotp[mi][reg], mask, 64);
  if (r == 0) {
#pragma unroll
    for (int mi = 0; mi < 4; ++mi)
#pragma unroll
      for (int reg = 0; reg < 4; ++reg)
        sRed[wu][mi * 16 + q * 4 + reg] = dotp[mi][reg];
  }
  __syncthreads();
  if (t < 64)
    out[m0 + t] = sRed[0][t] + sRed[1][t] + sRed[2][t] + sRed[3][t] + bout[0];
}

// ---------------- launcher ----------------

extern "C" void kernel_launch(void* const* d_in, const int* in_sizes, int n_in,
                              void* d_out, int out_size, void* d_ws, size_t ws_size,
                              hipStream_t stream) {
  const float* x         = (const float*)d_in[0];
  const float* positions = (const float*)d_in[1];
  const float* W_in      = (const float*)d_in[2];
  const float* b_in      = (const float*)d_in[3];
  const float* Wg1       = (const float*)d_in[4];
  const float* bg1       = (const float*)d_in[5];
  const float* Wg2       = (const float*)d_in[6];
  const float* bg2       = (const float*)d_in[7];
  const float* Wm        = (const float*)d_in[8];
  const float* bm        = (const float*)d_in[9];
  const float* Wu        = (const float*)d_in[10];
  const float* bu        = (const float*)d_in[11];
  const float* Wp        = (const float*)d_in[12];
  const float* W_out     = (const float*)d_in[13];
  const float* b_out     = (const float*)d_in[14];
  const int*   ei        = (const int*)d_in[15];
  float* out = (float*)d_out;

  // workspace layout — sequential, non-overlapping (pos stride-4: 1 MB each)
  char* ws = (char*)d_ws;
  unsigned short* hbf   = (unsigned short*)(ws);                 //   0       +32 MB
  unsigned short* X     = (unsigned short*)(ws +  33554432UL);   //  32 MB    +32 MB
  unsigned short* Zb    = (unsigned short*)(ws +  67108864UL);   //  64 MB    +32 MB
  unsigned short* aggb  = (unsigned short*)(ws + 100663296UL);   //  96 MB    +32 MB
  float*          posA  = (float*)(ws + 134217728UL);            // +1 MB (stride-4)
  float*          posB  = (float*)(ws + 135266304UL);            // +1 MB (stride-4)
  float*          g     = (float*)(ws + 136314880UL);            // +2 MB
  float*          h0    = (float*)(ws + 138412032UL);            // +32 KB
  unsigned short* Wt1   = (unsigned short*)(ws + 138444800UL);   // +512 KB (2 layers, frag-order)
  unsigned short* Wut   = (unsigned short*)(ws + 138969088UL);   // +512 KB (2 layers, frag-order)
  int*            deg   = (int*)(ws + 139493376UL);              // +256 KB
  int*            cur   = (int*)(ws + 139755520UL);              // +256 KB
  int*            bsum  = (int*)(ws + 140017664UL);              // +1 KB
  int*            rowptr= (int*)(ws + 140018688UL);              // +256 KB -> ends 140280832
  int*            src_s = (int*)(ws + 140280832UL);              // +1 MB   -> ends 141329408
  float*          Uc    = (float*)(ws + 141329408UL);            // +2.2 MB (2112x256 f32)

  // layer-0 rank-decomposition scratch (region reuse; all stream-ordered):
  //   hg  (1.06 MB bf16)  lives in the aggb region   (dead until edge0 writes aggb)
  //   Xc,Zc (2.1 MB f32)  live in the X / Zb regions (bf16 X/Zb only written in l1)
  unsigned short* hg = aggb;
  float*          Xc = (float*)X;
  float*          Zc = (float*)Zb;

  // ---- stage 1: zero degrees ----
  hipMemsetAsync(deg, 0, (size_t)NN_ * sizeof(int), stream);

  // ---- stage 2: all independent prep in ONE dispatch (deg | wconv | h0 | meand_g) ----
  mega1_kernel<<<3360, 256, 0, stream>>>(ei, deg, Wm, Wu, Wt1, Wut,
                                         x, W_in, b_in, h0,
                                         positions, Wg1, bg1, Wg2, bg2, g);

  // ---- stage 3: scan hierarchy ----
  scan1_kernel<<<256, 256, 0, stream>>>(deg, bsum);
  scan2_kernel<<<1, 256, 0, stream>>>(bsum);

  // ---- stage 4: scan3 | initpack (hbf, hg, pos4) ----
  mega2_kernel<<<8964, 256, 0, stream>>>(deg, bsum, cur, rowptr,
                                         h0, g, positions, hbf, hg, posA);

  // ---- stage 5: scatter | gemm1_small | Uc-small-GEMM ----
  mega3_kernel<<<1090, 256, 0, stream>>>(ei, cur, src_s, hg, Wt1, Wut, bm, Xc, Zc, Uc);

  // ---- layer 0: table-gather edge (L1-resident pos table) + rank-decomposed update GEMM ----
  edge0_kernel<<<NN_ / 4, 256, 0, stream>>>(Xc, Zc, posA, rowptr, src_s,
                                            Wm + 512 * H_, Wp, aggb, posB);
  upd2_dec<<<NN_ / 64, 256, 0, stream>>>(hbf, aggb, Wut + 65536, Uc, bu);

  // ---- layer 1: full path (bf16 X table; pos update dead in final layer) ----
  gemm1_mfma<<<NN_ / 64, 256, 0, stream>>>(hbf, Wt1 + 131072,
                                           bm + H_, X, Zb);
  edge_kernel<<<NN_ / 4, 256, 0, stream>>>(X, Zb, posB, rowptr, src_s,
                                           Wm + (size_t)513 * H_ + 512 * H_,
                                           aggb);
  upd2_out<<<NN_ / 64, 256, 0, stream>>>(hbf, aggb, Wut + 131072,
                                         bu + H_, W_out, b_out, out);
}